// Round 2
// baseline (3571.255 us; speedup 1.0000x reference)
//
#include <hip/hip_runtime.h>
#include <hip/hip_bf16.h>

// WaveNet forward, MI355X. Structure:
//  k1: bsum     -- bsSum[s] = sum_i bs[i][s]
//  k2: init     -- x0 = Wc @ y + bc                  (256->32 pointwise)
//  k3: layer x30-- dilated conv K=2, gates, g-out, residual (sequential)
//  k4: final    -- skip = WsAll@g_all (K=480), relu, e1, relu, e2, transpose
// g_all trick: skip accumulation deferred into one K=480 GEMM (saves 7.7GB HBM RMW).

#define B_ 4
#define T_ 32768
#define RC_ 32
#define KH_ 16          // DC/2
#define SC_ 256
#define CLASSES_ 256
#define NL_ 30

__device__ inline float fast_rcp(float x) { return __builtin_amdgcn_rcpf(x); }
__device__ inline float fast_sigmoid(float x) { return fast_rcp(1.f + __expf(-x)); }
__device__ inline float fast_tanh(float x) { return 1.f - 2.f * fast_rcp(__expf(2.f * x) + 1.f); }

__device__ inline float load_g(const float* p) { return *p; }
__device__ inline float load_g(const __hip_bfloat16* p) { return __bfloat162float(*p); }
__device__ inline void store_g(float* p, float v) { *p = v; }
__device__ inline void store_g(__hip_bfloat16* p, float v) { *p = __float2bfloat16(v); }

// ---------------- k1: bias sum -------------------------------------------
__global__ void bsum_kernel(const float* __restrict__ bs, float* __restrict__ bsSum) {
    int s = threadIdx.x;
    float v = 0.f;
    #pragma unroll
    for (int i = 0; i < NL_; ++i) v += bs[i * SC_ + s];
    bsSum[s] = v;
}

// ---------------- k2: initial 256->32 pointwise conv ---------------------
__global__ __launch_bounds__(256) void init_conv_kernel(
    const float* __restrict__ y, const float* __restrict__ Wc,
    const float* __restrict__ bc, float* __restrict__ x0)
{
    int gid = blockIdx.x * 256 + threadIdx.x;
    int b = gid >> 15;          // T = 2^15
    int t = gid & (T_ - 1);
    float acc[RC_];
    #pragma unroll
    for (int c = 0; c < RC_; ++c) acc[c] = bc[c];
    const float* yb = y + (size_t)b * CLASSES_ * T_ + t;
    for (int cb = 0; cb < CLASSES_; cb += 32) {
        float yv[32];
        #pragma unroll
        for (int j = 0; j < 32; ++j) yv[j] = yb[(size_t)(cb + j) * T_];
        #pragma unroll
        for (int c = 0; c < RC_; ++c) {
            #pragma unroll
            for (int j = 0; j < 32; ++j)
                acc[c] = fmaf(Wc[c * CLASSES_ + cb + j], yv[j], acc[c]);
        }
    }
    float* xo = x0 + (size_t)b * RC_ * T_ + t;
    #pragma unroll
    for (int c = 0; c < RC_; ++c) xo[(size_t)c * T_] = acc[c];
}

// ---------------- k3: one residual layer ---------------------------------
template <typename G>
__global__ __launch_bounds__(256) void layer_kernel(
    const float* __restrict__ x_in, float* __restrict__ x_out, G* __restrict__ g_out,
    const float* __restrict__ wf, const float* __restrict__ bfp,
    const float* __restrict__ wr, const float* __restrict__ brp, int d)
{
    int gid = blockIdx.x * 256 + threadIdx.x;
    int b = gid >> 15;
    int t = gid & (T_ - 1);
    const float* xbase = x_in + (size_t)b * RC_ * T_ + t;

    float xm[RC_], xd[RC_];
    #pragma unroll
    for (int ci = 0; ci < RC_; ++ci) xm[ci] = xbase[(size_t)ci * T_];
    #pragma unroll
    for (int ci = 0; ci < RC_; ++ci)
        xd[ci] = (t >= d) ? xbase[(size_t)ci * T_ - d] : 0.f;

    // h[c] = bf[c] + sum_ci wf[c][ci][0]*x[t-d] + wf[c][ci][1]*x[t]
    float a_[KH_];
    #pragma unroll
    for (int c = 0; c < KH_; ++c) {
        float s = bfp[c];
        #pragma unroll
        for (int ci = 0; ci < RC_; ++ci) {
            s = fmaf(wf[(c * RC_ + ci) * 2 + 0], xd[ci], s);
            s = fmaf(wf[(c * RC_ + ci) * 2 + 1], xm[ci], s);
        }
        a_[c] = s;
    }
    float g[KH_];
    #pragma unroll
    for (int c = 0; c < KH_; ++c) {
        float s = bfp[KH_ + c];
        #pragma unroll
        for (int ci = 0; ci < RC_; ++ci) {
            s = fmaf(wf[((KH_ + c) * RC_ + ci) * 2 + 0], xd[ci], s);
            s = fmaf(wf[((KH_ + c) * RC_ + ci) * 2 + 1], xm[ci], s);
        }
        g[c] = fast_tanh(a_[c]) * fast_sigmoid(s);
    }
    G* gb = g_out + (size_t)b * KH_ * T_ + t;
    #pragma unroll
    for (int c = 0; c < KH_; ++c) store_g(gb + (size_t)c * T_, g[c]);

    float* xo = x_out + (size_t)b * RC_ * T_ + t;
    #pragma unroll
    for (int c = 0; c < RC_; ++c) {
        float s = brp[c];
        #pragma unroll
        for (int ci = 0; ci < KH_; ++ci) s = fmaf(wr[c * KH_ + ci], g[ci], s);
        xo[(size_t)c * T_] = (s + xm[c]) * 0.70710678118654752f;
    }
}

// ---------------- k4: fused skip-GEMM + relu + e1 + relu + e2 + transpose -
// Tile: 16 time positions. Thread owns 4 channels (c4+{0,64,128,192}) x 4 t.
// LDS (57344 B): plds[256][20] @0, qlds[256][20] @5120, glds[480][16] @0
// (aliases p/q, dead before they're written), wlds[16][256] @10240.
template <typename G>
__global__ __launch_bounds__(256) void final_kernel(
    const G* __restrict__ g_all, const float* __restrict__ bsSum,
    const float* __restrict__ Ws, const float* __restrict__ We1,
    const float* __restrict__ be1, const float* __restrict__ We2,
    const float* __restrict__ be2, float* __restrict__ out)
{
    __shared__ float smem[14336];
    float* plds = smem;
    float* qlds = smem + 5120;
    float* glds = smem;
    float* wlds = smem + 10240;

    int tid = threadIdx.x;
    int bt = blockIdx.x;
    int b = bt >> 11;                 // 2048 tiles per batch
    int t0 = (bt & 2047) << 4;
    int c4 = tid & 63;
    int th = tid >> 6;                // t = t0 + th*4 + tt

    // stage g tile [480][16]
    for (int e = tid; e < 480 * 16; e += 256) {
        int row = e >> 4, col = e & 15;
        int i = row >> 4, ci = row & 15;
        glds[e] = load_g(g_all + ((size_t)(i * B_ + b) * KH_ + ci) * T_ + t0 + col);
    }
    __syncthreads();

    float acc[4][4];
    #pragma unroll
    for (int j = 0; j < 4; ++j) {
        float bv = bsSum[c4 + 64 * j];
        #pragma unroll
        for (int tt = 0; tt < 4; ++tt) acc[j][tt] = bv;
    }

    // ---- stage A: skip = WsAll @ g  (K = 480, chunked by layer) ----
    for (int i = 0; i < NL_; ++i) {
        const float4* wsrc = (const float4*)(Ws + ((size_t)i * 256 + tid) * 16);
        float4 w0 = wsrc[0], w1 = wsrc[1], w2 = wsrc[2], w3 = wsrc[3];
        __syncthreads();   // prior chunk's wlds readers done
        wlds[0 * 256 + tid] = w0.x;  wlds[1 * 256 + tid] = w0.y;
        wlds[2 * 256 + tid] = w0.z;  wlds[3 * 256 + tid] = w0.w;
        wlds[4 * 256 + tid] = w1.x;  wlds[5 * 256 + tid] = w1.y;
        wlds[6 * 256 + tid] = w1.z;  wlds[7 * 256 + tid] = w1.w;
        wlds[8 * 256 + tid] = w2.x;  wlds[9 * 256 + tid] = w2.y;
        wlds[10 * 256 + tid] = w2.z; wlds[11 * 256 + tid] = w2.w;
        wlds[12 * 256 + tid] = w3.x; wlds[13 * 256 + tid] = w3.y;
        wlds[14 * 256 + tid] = w3.z; wlds[15 * 256 + tid] = w3.w;
        __syncthreads();
        #pragma unroll
        for (int ci = 0; ci < 16; ++ci) {
            const float4 gv = *(const float4*)&glds[(i * 16 + ci) * 16 + th * 4];
            float wv[4];
            #pragma unroll
            for (int j = 0; j < 4; ++j) wv[j] = wlds[ci * 256 + c4 + 64 * j];
            #pragma unroll
            for (int j = 0; j < 4; ++j) {
                acc[j][0] = fmaf(wv[j], gv.x, acc[j][0]);
                acc[j][1] = fmaf(wv[j], gv.y, acc[j][1]);
                acc[j][2] = fmaf(wv[j], gv.z, acc[j][2]);
                acc[j][3] = fmaf(wv[j], gv.w, acc[j][3]);
            }
        }
    }
    __syncthreads();   // glds dead; safe to write plds
    #pragma unroll
    for (int j = 0; j < 4; ++j)
        #pragma unroll
        for (int tt = 0; tt < 4; ++tt)
            plds[(c4 + 64 * j) * 20 + th * 4 + tt] = fmaxf(acc[j][tt], 0.f);

    // ---- stage B: q = relu(We1 @ p + be1), K = 256 ----
    #pragma unroll
    for (int j = 0; j < 4; ++j) {
        float bv = be1[c4 + 64 * j];
        #pragma unroll
        for (int tt = 0; tt < 4; ++tt) acc[j][tt] = bv;
    }
    for (int kc = 0; kc < 16; ++kc) {
        const float4* wsrc = (const float4*)(We1 + (size_t)tid * 256 + kc * 16);
        float4 w0 = wsrc[0], w1 = wsrc[1], w2 = wsrc[2], w3 = wsrc[3];
        __syncthreads();
        wlds[0 * 256 + tid] = w0.x;  wlds[1 * 256 + tid] = w0.y;
        wlds[2 * 256 + tid] = w0.z;  wlds[3 * 256 + tid] = w0.w;
        wlds[4 * 256 + tid] = w1.x;  wlds[5 * 256 + tid] = w1.y;
        wlds[6 * 256 + tid] = w1.z;  wlds[7 * 256 + tid] = w1.w;
        wlds[8 * 256 + tid] = w2.x;  wlds[9 * 256 + tid] = w2.y;
        wlds[10 * 256 + tid] = w2.z; wlds[11 * 256 + tid] = w2.w;
        wlds[12 * 256 + tid] = w3.x; wlds[13 * 256 + tid] = w3.y;
        wlds[14 * 256 + tid] = w3.z; wlds[15 * 256 + tid] = w3.w;
        __syncthreads();
        #pragma unroll
        for (int kk = 0; kk < 16; ++kk) {
            const float4 pv = *(const float4*)&plds[(kc * 16 + kk) * 20 + th * 4];
            float wv[4];
            #pragma unroll
            for (int j = 0; j < 4; ++j) wv[j] = wlds[kk * 256 + c4 + 64 * j];
            #pragma unroll
            for (int j = 0; j < 4; ++j) {
                acc[j][0] = fmaf(wv[j], pv.x, acc[j][0]);
                acc[j][1] = fmaf(wv[j], pv.y, acc[j][1]);
                acc[j][2] = fmaf(wv[j], pv.z, acc[j][2]);
                acc[j][3] = fmaf(wv[j], pv.w, acc[j][3]);
            }
        }
    }
    __syncthreads();
    #pragma unroll
    for (int j = 0; j < 4; ++j)
        #pragma unroll
        for (int tt = 0; tt < 4; ++tt)
            qlds[(c4 + 64 * j) * 20 + th * 4 + tt] = fmaxf(acc[j][tt], 0.f);

    // ---- stage C: out = We2 @ q + be2, K = 256, transposed store ----
    #pragma unroll
    for (int j = 0; j < 4; ++j) {
        float bv = be2[c4 + 64 * j];
        #pragma unroll
        for (int tt = 0; tt < 4; ++tt) acc[j][tt] = bv;
    }
    for (int kc = 0; kc < 16; ++kc) {
        const float4* wsrc = (const float4*)(We2 + (size_t)tid * 256 + kc * 16);
        float4 w0 = wsrc[0], w1 = wsrc[1], w2 = wsrc[2], w3 = wsrc[3];
        __syncthreads();
        wlds[0 * 256 + tid] = w0.x;  wlds[1 * 256 + tid] = w0.y;
        wlds[2 * 256 + tid] = w0.z;  wlds[3 * 256 + tid] = w0.w;
        wlds[4 * 256 + tid] = w1.x;  wlds[5 * 256 + tid] = w1.y;
        wlds[6 * 256 + tid] = w1.z;  wlds[7 * 256 + tid] = w1.w;
        wlds[8 * 256 + tid] = w2.x;  wlds[9 * 256 + tid] = w2.y;
        wlds[10 * 256 + tid] = w2.z; wlds[11 * 256 + tid] = w2.w;
        wlds[12 * 256 + tid] = w3.x; wlds[13 * 256 + tid] = w3.y;
        wlds[14 * 256 + tid] = w3.z; wlds[15 * 256 + tid] = w3.w;
        __syncthreads();
        #pragma unroll
        for (int kk = 0; kk < 16; ++kk) {
            const float4 qv = *(const float4*)&qlds[(kc * 16 + kk) * 20 + th * 4];
            float wv[4];
            #pragma unroll
            for (int j = 0; j < 4; ++j) wv[j] = wlds[kk * 256 + c4 + 64 * j];
            #pragma unroll
            for (int j = 0; j < 4; ++j) {
                acc[j][0] = fmaf(wv[j], qv.x, acc[j][0]);
                acc[j][1] = fmaf(wv[j], qv.y, acc[j][1]);
                acc[j][2] = fmaf(wv[j], qv.z, acc[j][2]);
                acc[j][3] = fmaf(wv[j], qv.w, acc[j][3]);
            }
        }
    }
    #pragma unroll
    for (int tt = 0; tt < 4; ++tt) {
        size_t orow = ((size_t)b * T_ + t0 + th * 4 + tt) * 256;
        #pragma unroll
        for (int j = 0; j < 4; ++j)
            out[orow + c4 + 64 * j] = acc[j][tt];
    }
}

// ---------------- host -----------------------------------------------------
template <typename G>
static void run_pipeline(const float* y, const float* Wc, const float* bc,
                         const float* Wf, const float* bf, const float* Wr,
                         const float* br, const float* Ws, const float* bs,
                         const float* We1, const float* be1, const float* We2,
                         const float* be2, float* out, char* ws, hipStream_t stream)
{
    size_t xbytes = (size_t)B_ * RC_ * T_ * sizeof(float);
    float* xa = (float*)ws;
    float* xb = (float*)(ws + xbytes);
    G* g_all = (G*)(ws + 2 * xbytes);
    size_t gbytes = (size_t)NL_ * B_ * KH_ * T_ * sizeof(G);
    float* bsSum = (float*)(ws + 2 * xbytes + gbytes);

    bsum_kernel<<<1, 256, 0, stream>>>(bs, bsSum);
    init_conv_kernel<<<512, 256, 0, stream>>>(y, Wc, bc, xa);

    float* xin = xa;
    float* xout = xb;
    for (int i = 0; i < NL_; ++i) {
        int d = 1 << (i % 10);
        layer_kernel<G><<<512, 256, 0, stream>>>(
            xin, xout, g_all + (size_t)i * B_ * KH_ * T_,
            Wf + (size_t)i * RC_ * RC_ * 2, bf + (size_t)i * RC_,
            Wr + (size_t)i * RC_ * KH_, br + (size_t)i * RC_, d);
        float* tmp = xin; xin = xout; xout = tmp;
    }

    final_kernel<G><<<B_ * (T_ / 16), 256, 0, stream>>>(
        g_all, bsSum, Ws, We1, be1, We2, be2, out);
}

extern "C" void kernel_launch(void* const* d_in, const int* in_sizes, int n_in,
                              void* d_out, int out_size, void* d_ws, size_t ws_size,
                              hipStream_t stream)
{
    (void)in_sizes; (void)n_in; (void)out_size;
    const float* y   = (const float*)d_in[0];
    const float* Wc  = (const float*)d_in[1];
    const float* bc  = (const float*)d_in[2];
    const float* Wf  = (const float*)d_in[3];
    const float* bf  = (const float*)d_in[4];
    const float* Wr  = (const float*)d_in[5];
    const float* br  = (const float*)d_in[6];
    const float* Ws  = (const float*)d_in[7];
    const float* bs  = (const float*)d_in[8];
    const float* We1 = (const float*)d_in[9];
    const float* be1 = (const float*)d_in[10];
    const float* We2 = (const float*)d_in[11];
    const float* be2 = (const float*)d_in[12];
    float* out = (float*)d_out;
    char* ws = (char*)d_ws;

    size_t xbytes = (size_t)B_ * RC_ * T_ * sizeof(float);
    size_t need_f32 = 2 * xbytes + (size_t)NL_ * B_ * KH_ * T_ * 4 + 1024;

    if (ws_size >= need_f32) {
        run_pipeline<float>(y, Wc, bc, Wf, bf, Wr, br, Ws, bs, We1, be1, We2, be2,
                            out, ws, stream);
    } else {
        run_pipeline<__hip_bfloat16>(y, Wc, bc, Wf, bf, Wr, br, Ws, bs, We1, be1,
                                     We2, be2, out, ws, stream);
    }
}

// Round 5
// 727.277 us; speedup vs baseline: 4.9104x; 4.9104x over previous
//
#include <hip/hip_runtime.h>
#include <hip/hip_bf16.h>

// WaveNet forward, MI355X — MFMA pipeline v2 (fits ws in [159.4, 285) MB).
//  prep_w    : weights -> bf16 fragment layouts
//  prep_y    : y [b][256][T] fp32 -> y_t [t'][512] bf16 {hi|lo}
//  init_gemm : x0 = Wc@y + bc, K=768 = [hi|hi|lo]@[yh|yl|yh] (one pass, bf16 out)
//  layer x30 : h=Wf·{x[t-d],x[t]} (MFMA), gates (VALU), r=Wr·g (MFMA), residual
//  tail      : FUSED skip(K=480)->relu->e1->relu->e2->transpose; p/q in LDS.
// Memory: y_t region (134.2MB) reused for g (125.8MB); x bf16 ping-pong 16.8MB;
// weights 0.7MB. Total 151.7MB.

#define B_ 4
#define T_ 32768
#define RC_ 32
#define KH_ 16
#define SC_ 256
#define CLASSES_ 256
#define NL_ 30
#define NT_ 131072L   // B_*T_

using f32x4 = __attribute__((ext_vector_type(4))) float;
using s16x8 = __attribute__((ext_vector_type(8))) short;

__device__ inline float fast_rcp(float x) { return __builtin_amdgcn_rcpf(x); }
__device__ inline float fast_sigmoid(float x) { return fast_rcp(1.f + __expf(-x)); }
__device__ inline float fast_tanh(float x) { return 1.f - 2.f * fast_rcp(__expf(2.f * x) + 1.f); }

__device__ inline ushort f2bf(float v) {
    __hip_bfloat16 h = __float2bfloat16(v);
    return __builtin_bit_cast(ushort, h);
}
__device__ inline uint pack2(float a, float b) {
    return (uint)f2bf(a) | ((uint)f2bf(b) << 16);
}
__device__ inline float bflo(uint u) { return __builtin_bit_cast(float, u << 16); }
__device__ inline float bfhi(uint u) { return __builtin_bit_cast(float, u & 0xffff0000u); }
__device__ inline s16x8 mfma_in(uint4 u) { return __builtin_bit_cast(s16x8, u); }

// ======================= prep: weights =====================================
// element counts: wcp 24576 | wfp 61440 | wrp 30720 | wst 122880 | we1 65536 | we2 65536
__global__ __launch_bounds__(256) void prep_w_kernel(
    const float* __restrict__ Wc, const float* __restrict__ Wf,
    const float* __restrict__ Wr, const float* __restrict__ Ws,
    const float* __restrict__ We1, const float* __restrict__ We2,
    ushort* __restrict__ wcp, ushort* __restrict__ wfp, ushort* __restrict__ wrp,
    ushort* __restrict__ wst, ushort* __restrict__ we1b, ushort* __restrict__ we2b)
{
    int j = blockIdx.x * 256 + threadIdx.x;
    if (j < 24576) {                       // WcP[32][768] = [hi | hi | lo]
        int m = j / 768, k = j % 768;
        float v = Wc[m * 256 + (k & 255)];
        if (k < 512) wcp[j] = f2bf(v);
        else {
            float hi = __bfloat162float(__float2bfloat16(v));
            wcp[j] = f2bf(v - hi);
        }
    } else if (j < 86016) {                // WfP[30][2][32][32]  (tap, out c, in ci)
        int e = j - 24576;
        int i = e >> 11; int r = e & 2047;
        int tap = r >> 10, c = (r >> 5) & 31, ci = r & 31;
        wfp[e] = f2bf(Wf[((size_t)(i * 32 + c) * 32 + ci) * 2 + tap]);
    } else if (j < 116736) {               // WrP[30][32][32] zero-padded k>=16
        int e = j - 86016;
        int i = e >> 10; int c = (e >> 5) & 31; int k = e & 31;
        wrp[e] = (k < 16) ? f2bf(Wr[(size_t)(i * 32 + c) * 16 + k]) : (ushort)0;
    } else if (j < 239616) {               // WsT[256][480], k = layer*16 + ci
        int e = j - 116736;
        int s = e / 480, k = e % 480;
        int i = k >> 4, ci = k & 15;
        wst[e] = f2bf(Ws[(size_t)(i * 256 + s) * 16 + ci]);
    } else if (j < 305152) {
        int e = j - 239616; we1b[e] = f2bf(We1[e]);
    } else if (j < 370688) {
        int e = j - 305152; we2b[e] = f2bf(We2[e]);
    }
}

__global__ void bsum_kernel(const float* __restrict__ bs, float* __restrict__ bsSum) {
    int s = threadIdx.x;
    float v = 0.f;
    #pragma unroll
    for (int i = 0; i < NL_; ++i) v += bs[i * SC_ + s];
    bsSum[s] = v;
}

// ======================= prep: y transpose + hi/lo split ===================
__global__ __launch_bounds__(256) void prep_y_kernel(
    const float* __restrict__ y, ushort* __restrict__ y_t)
{
    __shared__ float lds[32][65];
    int tid = threadIdx.x;
    int b = blockIdx.x >> 9;
    long t0 = (long)(blockIdx.x & 511) * 64;
    for (int cc = 0; cc < 8; ++cc) {
        int c = cc * 32 + (tid >> 3);
        int tp = (tid & 7) * 8;
        const float* src = y + ((size_t)b * 256 + c) * T_ + t0 + tp;
        float4 v0 = *(const float4*)src;
        float4 v1 = *(const float4*)(src + 4);
        lds[tid >> 3][tp + 0] = v0.x; lds[tid >> 3][tp + 1] = v0.y;
        lds[tid >> 3][tp + 2] = v0.z; lds[tid >> 3][tp + 3] = v0.w;
        lds[tid >> 3][tp + 4] = v1.x; lds[tid >> 3][tp + 5] = v1.y;
        lds[tid >> 3][tp + 6] = v1.z; lds[tid >> 3][tp + 7] = v1.w;
        __syncthreads();
        int t = tid & 63, cp = tid >> 6;
        float v[8];
        #pragma unroll
        for (int jj = 0; jj < 8; ++jj) v[jj] = lds[cp * 8 + jj][t];
        uint hi[4], lo[4];
        #pragma unroll
        for (int jj = 0; jj < 4; ++jj) {
            float a = v[2 * jj], bv = v[2 * jj + 1];
            float ah = __bfloat162float(__float2bfloat16(a));
            float bh = __bfloat162float(__float2bfloat16(bv));
            hi[jj] = pack2(a, bv);
            lo[jj] = pack2(a - ah, bv - bh);
        }
        ushort* dst = y_t + ((size_t)b * T_ + t0 + t) * 512 + cc * 32 + cp * 8;
        *(uint4*)dst = make_uint4(hi[0], hi[1], hi[2], hi[3]);
        *(uint4*)(dst + 256) = make_uint4(lo[0], lo[1], lo[2], lo[3]);
        __syncthreads();
    }
}

// ======================= init GEMM: x0 = Wc@y + bc =========================
// A = wcp [32][768]; B rows = y_t[t][512] with k>=512 wrapping to k-512 (yh).
__global__ __launch_bounds__(256) void init_gemm_kernel(
    const ushort* __restrict__ wcp, const ushort* __restrict__ y_t,
    const float* __restrict__ bc, ushort* __restrict__ x0)
{
    __shared__ ushort sa[2][32 * 40];
    __shared__ ushort sb[2][256 * 40];
    int tid = threadIdx.x;
    int wid = tid >> 6, lane = tid & 63, q = lane >> 4, ln = lane & 15;
    long n0 = (long)blockIdx.x * 256;

    uint4 ar0, ar1, br0, br1, br2, br3;
    auto load_tile = [&](int kc) {
        int k0 = kc * 32;
        int koff = (k0 < 512) ? k0 : k0 - 512;
        if (tid < 64) {
            int m = tid >> 1, h = tid & 1;
            const uint4* s = (const uint4*)(wcp + m * 768 + k0 + h * 16);
            ar0 = s[0]; ar1 = s[1];
        }
        const uint4* sB = (const uint4*)(y_t + (n0 + tid) * 512 + koff);
        br0 = sB[0]; br1 = sB[1]; br2 = sB[2]; br3 = sB[3];
    };
    auto store_tile = [&](int buf) {
        if (tid < 64) {
            int m = tid >> 1, h = tid & 1;
            *(uint4*)&sa[buf][m * 40 + h * 16] = ar0;
            *(uint4*)&sa[buf][m * 40 + h * 16 + 8] = ar1;
        }
        *(uint4*)&sb[buf][tid * 40 + 0]  = br0;
        *(uint4*)&sb[buf][tid * 40 + 8]  = br1;
        *(uint4*)&sb[buf][tid * 40 + 16] = br2;
        *(uint4*)&sb[buf][tid * 40 + 24] = br3;
    };

    f32x4 acc[2][4];
    #pragma unroll
    for (int mi = 0; mi < 2; ++mi) {
        f32x4 bv = *(const f32x4*)&bc[mi * 16 + 4 * q];
        #pragma unroll
        for (int ni = 0; ni < 4; ++ni) acc[mi][ni] = bv;
    }
    load_tile(0);
    for (int kc = 0; kc < 24; ++kc) {
        int buf = kc & 1;
        store_tile(buf);
        __syncthreads();
        if (kc + 1 < 24) load_tile(kc + 1);
        s16x8 af[2];
        #pragma unroll
        for (int mi = 0; mi < 2; ++mi)
            af[mi] = mfma_in(*(const uint4*)&sa[buf][(mi * 16 + ln) * 40 + q * 8]);
        #pragma unroll
        for (int ni = 0; ni < 4; ++ni) {
            s16x8 bfr = mfma_in(*(const uint4*)&sb[buf][(wid * 64 + ni * 16 + ln) * 40 + q * 8]);
            #pragma unroll
            for (int mi = 0; mi < 2; ++mi)
                acc[mi][ni] = __builtin_amdgcn_mfma_f32_16x16x32_bf16(af[mi], bfr, acc[mi][ni], 0, 0, 0);
        }
        __syncthreads();
    }
    #pragma unroll
    for (int mi = 0; mi < 2; ++mi) {
        int ch = mi * 16 + 4 * q;
        #pragma unroll
        for (int ni = 0; ni < 4; ++ni) {
            long t = n0 + wid * 64 + ni * 16 + ln;
            f32x4 v = acc[mi][ni];
            uint2 pk; pk.x = pack2(v[0], v[1]); pk.y = pack2(v[2], v[3]);
            *(uint2*)&x0[t * 32 + ch] = pk;
        }
    }
}

// ======================= layer (MFMA, bf16 x) ==============================
__global__ __launch_bounds__(256) void layer_mfma_kernel(
    const ushort* __restrict__ xb_in, ushort* __restrict__ xb_out,
    ushort* __restrict__ g_out,
    const ushort* __restrict__ wfp, const ushort* __restrict__ wrp,
    const float* __restrict__ bfp, const float* __restrict__ brp, int d)
{
    int tid = threadIdx.x;
    int wid = tid >> 6, lane = tid & 63, q = lane >> 4, ln = lane & 15;
    long tw = (long)blockIdx.x * 128 + wid * 32;

    s16x8 wfA[2][2], wrA[2];
    #pragma unroll
    for (int mb = 0; mb < 2; ++mb) {
        #pragma unroll
        for (int tap = 0; tap < 2; ++tap)
            wfA[mb][tap] = mfma_in(*(const uint4*)&wfp[(tap * 32 + mb * 16 + ln) * 32 + q * 8]);
        wrA[mb] = mfma_in(*(const uint4*)&wrp[(mb * 16 + ln) * 32 + q * 8]);
    }
    f32x4 bfv0 = *(const f32x4*)&bfp[4 * q];
    f32x4 bfv1 = *(const f32x4*)&bfp[16 + 4 * q];
    f32x4 brv0 = *(const f32x4*)&brp[4 * q];
    f32x4 brv1 = *(const f32x4*)&brp[16 + 4 * q];
    const float inv_s2 = 0.70710678118654752f;

    #pragma unroll
    for (int nb = 0; nb < 2; ++nb) {
        long t = tw + nb * 16 + ln;
        bool vok = ((int)(t & (T_ - 1)) >= d);
        long r0 = vok ? (t - d) : t;
        uint4 u0 = *(const uint4*)&xb_in[r0 * 32 + 8 * q];
        if (!vok) u0 = make_uint4(0, 0, 0, 0);
        uint4 u1 = *(const uint4*)&xb_in[t * 32 + 8 * q];
        s16x8 b0 = mfma_in(u0), b1 = mfma_in(u1);

        f32x4 h0 = {}, h1 = {};
        h0 = __builtin_amdgcn_mfma_f32_16x16x32_bf16(wfA[0][0], b0, h0, 0, 0, 0);
        h0 = __builtin_amdgcn_mfma_f32_16x16x32_bf16(wfA[0][1], b1, h0, 0, 0, 0);
        h1 = __builtin_amdgcn_mfma_f32_16x16x32_bf16(wfA[1][0], b0, h1, 0, 0, 0);
        h1 = __builtin_amdgcn_mfma_f32_16x16x32_bf16(wfA[1][1], b1, h1, 0, 0, 0);

        float g[4];
        #pragma unroll
        for (int r = 0; r < 4; ++r)
            g[r] = fast_tanh(h0[r] + bfv0[r]) * fast_sigmoid(h1[r] + bfv1[r]);
        uint p01 = pack2(g[0], g[1]), p23 = pack2(g[2], g[3]);
        uint2 gst; gst.x = p01; gst.y = p23;
        *(uint2*)&g_out[t * 16 + 4 * q] = gst;

        // redistribute C-layout g (ch 4q+r @ t=ln) -> B-fragment (ch 8q+j @ t=ln)
        int sA = q * 32 + ln;   // >=64 wraps; those feed zero-padded Wr rows
        uint f0 = (uint)__shfl((int)p01, sA);
        uint f1 = (uint)__shfl((int)p23, sA);
        uint f2 = (uint)__shfl((int)p01, sA + 16);
        uint f3 = (uint)__shfl((int)p23, sA + 16);
        s16x8 gb = mfma_in(make_uint4(f0, f1, f2, f3));

        f32x4 rr0 = {}, rr1 = {};
        rr0 = __builtin_amdgcn_mfma_f32_16x16x32_bf16(wrA[0], gb, rr0, 0, 0, 0);
        rr1 = __builtin_amdgcn_mfma_f32_16x16x32_bf16(wrA[1], gb, rr1, 0, 0, 0);

        uint2 xr0 = *(const uint2*)&xb_in[t * 32 + 4 * q];
        uint2 xr1 = *(const uint2*)&xb_in[t * 32 + 16 + 4 * q];
        float o00 = (rr0[0] + brv0[0] + bflo(xr0.x)) * inv_s2;
        float o01 = (rr0[1] + brv0[1] + bfhi(xr0.x)) * inv_s2;
        float o02 = (rr0[2] + brv0[2] + bflo(xr0.y)) * inv_s2;
        float o03 = (rr0[3] + brv0[3] + bfhi(xr0.y)) * inv_s2;
        float o10 = (rr1[0] + brv1[0] + bflo(xr1.x)) * inv_s2;
        float o11 = (rr1[1] + brv1[1] + bfhi(xr1.x)) * inv_s2;
        float o12 = (rr1[2] + brv1[2] + bflo(xr1.y)) * inv_s2;
        float o13 = (rr1[3] + brv1[3] + bfhi(xr1.y)) * inv_s2;
        uint2 xp0; xp0.x = pack2(o00, o01); xp0.y = pack2(o02, o03);
        uint2 xp1; xp1.x = pack2(o10, o11); xp1.y = pack2(o12, o13);
        *(uint2*)&xb_out[t * 32 + 4 * q] = xp0;
        *(uint2*)&xb_out[t * 32 + 16 + 4 * q] = xp1;
    }
}

// ======================= fused tail ========================================
// Per block: 64 times, all 256 channels. Phase1 skip(K=480) -> p panels (LDS)
// Phase2 e1(K=256) -> q panels (in-place) Phase3 e2(K=256) -> out fp32 [t][256].
// pq: 8 panels of [64 t][40] (32 ch each). sb (g staging) aliases panel 0.
__global__ __launch_bounds__(256) void tail_kernel(
    const ushort* __restrict__ g_all, const float* __restrict__ bsSum,
    const ushort* __restrict__ wst, const ushort* __restrict__ we1b,
    const ushort* __restrict__ we2b, const float* __restrict__ be1,
    const float* __restrict__ be2, float* __restrict__ out)
{
    __shared__ ushort sa[256 * 40];      // 20480 B
    __shared__ ushort pq[8 * 64 * 40];   // 40960 B
    ushort* sb = pq;                     // alias: g staging, skip phase only
    int tid = threadIdx.x;
    int wid = tid >> 6, lane = tid & 63, q = lane >> 4, ln = lane & 15;
    long n0 = (long)blockIdx.x * 64;
    int wrow = wid * 64;

    f32x4 acc[4][4];
    // ---------- phase 1: skip ----------
    #pragma unroll
    for (int mi = 0; mi < 4; ++mi) {
        f32x4 bv = *(const f32x4*)&bsSum[wrow + mi * 16 + 4 * q];
        #pragma unroll
        for (int ni = 0; ni < 4; ++ni) acc[mi][ni] = bv;
    }
    for (int kc = 0; kc < 15; ++kc) {
        __syncthreads();
        {
            const uint4* s = (const uint4*)(wst + (size_t)tid * 480 + kc * 32);
            uint4 a0 = s[0], a1 = s[1], a2 = s[2], a3 = s[3];
            *(uint4*)&sa[tid * 40 + 0]  = a0;
            *(uint4*)&sa[tid * 40 + 8]  = a1;
            *(uint4*)&sa[tid * 40 + 16] = a2;
            *(uint4*)&sa[tid * 40 + 24] = a3;
        }
        {
            int n = tid & 63, ip = (tid >> 6) & 1, half = tid >> 7;
            uint4 b0 = *(const uint4*)(g_all +
                ((size_t)(2 * kc + ip) * NT_ + n0 + n) * 16 + half * 8);
            *(uint4*)&sb[n * 40 + ip * 16 + half * 8] = b0;
        }
        __syncthreads();
        s16x8 af[4];
        #pragma unroll
        for (int mi = 0; mi < 4; ++mi)
            af[mi] = mfma_in(*(const uint4*)&sa[(wrow + mi * 16 + ln) * 40 + q * 8]);
        #pragma unroll
        for (int ni = 0; ni < 4; ++ni) {
            s16x8 bfr = mfma_in(*(const uint4*)&sb[(ni * 16 + ln) * 40 + q * 8]);
            #pragma unroll
            for (int mi = 0; mi < 4; ++mi)
                acc[mi][ni] = __builtin_amdgcn_mfma_f32_16x16x32_bf16(af[mi], bfr, acc[mi][ni], 0, 0, 0);
        }
    }
    __syncthreads();   // all sb reads done before p overwrites panel 0
    #pragma unroll
    for (int mi = 0; mi < 4; ++mi) {
        int ch = wrow + mi * 16 + 4 * q;
        int base = (ch >> 5) * 2560, c5 = ch & 31;
        #pragma unroll
        for (int ni = 0; ni < 4; ++ni) {
            f32x4 v = acc[mi][ni];
            int ta = base + (ni * 16 + ln) * 40 + c5;
            *(uint*)&pq[ta]     = pack2(fmaxf(v[0], 0.f), fmaxf(v[1], 0.f));
            *(uint*)&pq[ta + 2] = pack2(fmaxf(v[2], 0.f), fmaxf(v[3], 0.f));
        }
    }
    // ---------- phase 2: e1 ----------
    #pragma unroll
    for (int mi = 0; mi < 4; ++mi) {
        f32x4 bv = *(const f32x4*)&be1[wrow + mi * 16 + 4 * q];
        #pragma unroll
        for (int ni = 0; ni < 4; ++ni) acc[mi][ni] = bv;
    }
    for (int kc = 0; kc < 8; ++kc) {
        __syncthreads();
        {
            const uint4* s = (const uint4*)(we1b + (size_t)tid * 256 + kc * 32);
            uint4 a0 = s[0], a1 = s[1], a2 = s[2], a3 = s[3];
            *(uint4*)&sa[tid * 40 + 0]  = a0;
            *(uint4*)&sa[tid * 40 + 8]  = a1;
            *(uint4*)&sa[tid * 40 + 16] = a2;
            *(uint4*)&sa[tid * 40 + 24] = a3;
        }
        __syncthreads();
        s16x8 af[4];
        #pragma unroll
        for (int mi = 0; mi < 4; ++mi)
            af[mi] = mfma_in(*(const uint4*)&sa[(wrow + mi * 16 + ln) * 40 + q * 8]);
        #pragma unroll
        for (int ni = 0; ni < 4; ++ni) {
            s16x8 bfr = mfma_in(*(const uint4*)&pq[kc * 2560 + (ni * 16 + ln) * 40 + q * 8]);
            #pragma unroll
            for (int mi = 0; mi < 4; ++mi)
                acc[mi][ni] = __builtin_amdgcn_mfma_f32_16x16x32_bf16(af[mi], bfr, acc[mi][ni], 0, 0, 0);
        }
    }
    __syncthreads();   // all p reads done before q overwrites
    #pragma unroll
    for (int mi = 0; mi < 4; ++mi) {
        int ch = wrow + mi * 16 + 4 * q;
        int base = (ch >> 5) * 2560, c5 = ch & 31;
        #pragma unroll
        for (int ni = 0; ni < 4; ++ni) {
            f32x4 v = acc[mi][ni];
            int ta = base + (ni * 16 + ln) * 40 + c5;
            *(uint*)&pq[ta]     = pack2(fmaxf(v[0], 0.f), fmaxf(v[1], 0.f));
            *(uint*)&pq[ta + 2] = pack2(fmaxf(v[2], 0.f), fmaxf(v[3], 0.f));
        }
    }
    // ---------- phase 3: e2 ----------
    #pragma unroll
    for (int mi = 0; mi < 4; ++mi) {
        f32x4 bv = *(const f32x4*)&be2[wrow + mi * 16 + 4 * q];
        #pragma unroll
        for (int ni = 0; ni < 4; ++ni) acc[mi][ni] = bv;
    }
    for (int kc = 0; kc < 8; ++kc) {
        __syncthreads();
        {
            const uint4* s = (const uint4*)(we2b + (size_t)tid * 256 + kc * 32);
            uint4 a0 = s[0], a1 = s[1], a2 = s[2], a3 = s[3];
            *(uint4*)&sa[tid * 40 + 0]  = a0;
            *(uint4*)&sa[tid * 40 + 8]  = a1;
            *(uint4*)&sa[tid * 40 + 16] = a2;
            *(uint4*)&sa[tid * 40 + 24] = a3;
        }
        __syncthreads();
        s16x8 af[4];
        #pragma unroll
        for (int mi = 0; mi < 4; ++mi)
            af[mi] = mfma_in(*(const uint4*)&sa[(wrow + mi * 16 + ln) * 40 + q * 8]);
        #pragma unroll
        for (int ni = 0; ni < 4; ++ni) {
            s16x8 bfr = mfma_in(*(const uint4*)&pq[kc * 2560 + (ni * 16 + ln) * 40 + q * 8]);
            #pragma unroll
            for (int mi = 0; mi < 4; ++mi)
                acc[mi][ni] = __builtin_amdgcn_mfma_f32_16x16x32_bf16(af[mi], bfr, acc[mi][ni], 0, 0, 0);
        }
    }
    #pragma unroll
    for (int mi = 0; mi < 4; ++mi) {
        int ch = wrow + mi * 16 + 4 * q;
        #pragma unroll
        for (int ni = 0; ni < 4; ++ni) {
            long t = n0 + ni * 16 + ln;
            *(f32x4*)&out[t * 256 + ch] = acc[mi][ni];
        }
    }
}

// ======================= OLD fallback pipeline (round-2, passing) ==========
__device__ inline float load_g(const float* p) { return *p; }
__device__ inline float load_g(const __hip_bfloat16* p) { return __bfloat162float(*p); }
__device__ inline void store_g(float* p, float v) { *p = v; }
__device__ inline void store_g(__hip_bfloat16* p, float v) { *p = __float2bfloat16(v); }

__global__ __launch_bounds__(256) void init_conv_kernel(
    const float* __restrict__ y, const float* __restrict__ Wc,
    const float* __restrict__ bc, float* __restrict__ x0)
{
    int gid = blockIdx.x * 256 + threadIdx.x;
    int b = gid >> 15;
    int t = gid & (T_ - 1);
    float acc[RC_];
    #pragma unroll
    for (int c = 0; c < RC_; ++c) acc[c] = bc[c];
    const float* yb = y + (size_t)b * CLASSES_ * T_ + t;
    for (int cb = 0; cb < CLASSES_; cb += 32) {
        float yv[32];
        #pragma unroll
        for (int j = 0; j < 32; ++j) yv[j] = yb[(size_t)(cb + j) * T_];
        #pragma unroll
        for (int c = 0; c < RC_; ++c)
            #pragma unroll
            for (int j = 0; j < 32; ++j)
                acc[c] = fmaf(Wc[c * CLASSES_ + cb + j], yv[j], acc[c]);
    }
    float* xo = x0 + (size_t)b * RC_ * T_ + t;
    #pragma unroll
    for (int c = 0; c < RC_; ++c) xo[(size_t)c * T_] = acc[c];
}

template <typename G>
__global__ __launch_bounds__(256) void layer_kernel(
    const float* __restrict__ x_in, float* __restrict__ x_out, G* __restrict__ g_out,
    const float* __restrict__ wf, const float* __restrict__ bfp,
    const float* __restrict__ wr, const float* __restrict__ brp, int d)
{
    int gid = blockIdx.x * 256 + threadIdx.x;
    int b = gid >> 15;
    int t = gid & (T_ - 1);
    const float* xbase = x_in + (size_t)b * RC_ * T_ + t;
    float xm[RC_], xd[RC_];
    #pragma unroll
    for (int ci = 0; ci < RC_; ++ci) xm[ci] = xbase[(size_t)ci * T_];
    #pragma unroll
    for (int ci = 0; ci < RC_; ++ci)
        xd[ci] = (t >= d) ? xbase[(size_t)ci * T_ - d] : 0.f;
    float a_[KH_];
    #pragma unroll
    for (int c = 0; c < KH_; ++c) {
        float s = bfp[c];
        #pragma unroll
        for (int ci = 0; ci < RC_; ++ci) {
            s = fmaf(wf[(c * RC_ + ci) * 2 + 0], xd[ci], s);
            s = fmaf(wf[(c * RC_ + ci) * 2 + 1], xm[ci], s);
        }
        a_[c] = s;
    }
    float g[KH_];
    #pragma unroll
    for (int c = 0; c < KH_; ++c) {
        float s = bfp[KH_ + c];
        #pragma unroll
        for (int ci = 0; ci < RC_; ++ci) {
            s = fmaf(wf[((KH_ + c) * RC_ + ci) * 2 + 0], xd[ci], s);
            s = fmaf(wf[((KH_ + c) * RC_ + ci) * 2 + 1], xm[ci], s);
        }
        g[c] = fast_tanh(a_[c]) * fast_sigmoid(s);
    }
    G* gb = g_out + (size_t)b * KH_ * T_ + t;
    #pragma unroll
    for (int c = 0; c < KH_; ++c) store_g(gb + (size_t)c * T_, g[c]);
    float* xo = x_out + (size_t)b * RC_ * T_ + t;
    #pragma unroll
    for (int c = 0; c < RC_; ++c) {
        float s = brp[c];
        #pragma unroll
        for (int ci = 0; ci < KH_; ++ci) s = fmaf(wr[c * KH_ + ci], g[ci], s);
        xo[(size_t)c * T_] = (s + xm[c]) * 0.70710678118654752f;
    }
}

template <typename G>
__global__ __launch_bounds__(256) void final_kernel(
    const G* __restrict__ g_all, const float* __restrict__ bsSum,
    const float* __restrict__ Ws, const float* __restrict__ We1,
    const float* __restrict__ be1, const float* __restrict__ We2,
    const float* __restrict__ be2, float* __restrict__ out)
{
    __shared__ float smem[14336];
    float* plds = smem;
    float* qlds = smem + 5120;
    float* glds = smem;
    float* wlds = smem + 10240;
    int tid = threadIdx.x;
    int bt = blockIdx.x;
    int b = bt >> 11;
    int t0 = (bt & 2047) << 4;
    int c4 = tid & 63;
    int th = tid >> 6;
    for (int e = tid; e < 480 * 16; e += 256) {
        int row = e >> 4, col = e & 15;
        int i = row >> 4, ci = row & 15;
        glds[e] = load_g(g_all + ((size_t)(i * B_ + b) * KH_ + ci) * T_ + t0 + col);
    }
    __syncthreads();
    float acc[4][4];
    #pragma unroll
    for (int j = 0; j < 4; ++j) {
        float bv = bsSum[c4 + 64 * j];
        #pragma unroll
        for (int tt = 0; tt < 4; ++tt) acc[j][tt] = bv;
    }
    for (int i = 0; i < NL_; ++i) {
        const float4* wsrc = (const float4*)(Ws + ((size_t)i * 256 + tid) * 16);
        float4 w0 = wsrc[0], w1 = wsrc[1], w2 = wsrc[2], w3 = wsrc[3];
        __syncthreads();
        wlds[0*256+tid]=w0.x; wlds[1*256+tid]=w0.y; wlds[2*256+tid]=w0.z; wlds[3*256+tid]=w0.w;
        wlds[4*256+tid]=w1.x; wlds[5*256+tid]=w1.y; wlds[6*256+tid]=w1.z; wlds[7*256+tid]=w1.w;
        wlds[8*256+tid]=w2.x; wlds[9*256+tid]=w2.y; wlds[10*256+tid]=w2.z; wlds[11*256+tid]=w2.w;
        wlds[12*256+tid]=w3.x; wlds[13*256+tid]=w3.y; wlds[14*256+tid]=w3.z; wlds[15*256+tid]=w3.w;
        __syncthreads();
        #pragma unroll
        for (int ci = 0; ci < 16; ++ci) {
            const float4 gv = *(const float4*)&glds[(i * 16 + ci) * 16 + th * 4];
            float wv[4];
            #pragma unroll
            for (int j = 0; j < 4; ++j) wv[j] = wlds[ci * 256 + c4 + 64 * j];
            #pragma unroll
            for (int j = 0; j < 4; ++j) {
                acc[j][0] = fmaf(wv[j], gv.x, acc[j][0]);
                acc[j][1] = fmaf(wv[j], gv.y, acc[j][1]);
                acc[j][2] = fmaf(wv[j], gv.z, acc[j][2]);
                acc[j][3] = fmaf(wv[j], gv.w, acc[j][3]);
            }
        }
    }
    __syncthreads();
    #pragma unroll
    for (int j = 0; j < 4; ++j)
        #pragma unroll
        for (int tt = 0; tt < 4; ++tt)
            plds[(c4 + 64 * j) * 20 + th * 4 + tt] = fmaxf(acc[j][tt], 0.f);
    #pragma unroll
    for (int j = 0; j < 4; ++j) {
        float bv = be1[c4 + 64 * j];
        #pragma unroll
        for (int tt = 0; tt < 4; ++tt) acc[j][tt] = bv;
    }
    for (int kc = 0; kc < 16; ++kc) {
        const float4* wsrc = (const float4*)(We1 + (size_t)tid * 256 + kc * 16);
        float4 w0 = wsrc[0], w1 = wsrc[1], w2 = wsrc[2], w3 = wsrc[3];
        __syncthreads();
        wlds[0*256+tid]=w0.x; wlds[1*256+tid]=w0.y; wlds[2*256+tid]=w0.z; wlds[3*256+tid]=w0.w;
        wlds[4*256+tid]=w1.x; wlds[5*256+tid]=w1.y; wlds[6*256+tid]=w1.z; wlds[7*256+tid]=w1.w;
        wlds[8*256+tid]=w2.x; wlds[9*256+tid]=w2.y; wlds[10*256+tid]=w2.z; wlds[11*256+tid]=w2.w;
        wlds[12*256+tid]=w3.x; wlds[13*256+tid]=w3.y; wlds[14*256+tid]=w3.z; wlds[15*256+tid]=w3.w;
        __syncthreads();
        #pragma unroll
        for (int kk = 0; kk < 16; ++kk) {
            const float4 pv = *(const float4*)&plds[(kc * 16 + kk) * 20 + th * 4];
            float wv[4];
            #pragma unroll
            for (int j = 0; j < 4; ++j) wv[j] = wlds[kk * 256 + c4 + 64 * j];
            #pragma unroll
            for (int j = 0; j < 4; ++j) {
                acc[j][0] = fmaf(wv[j], pv.x, acc[j][0]);
                acc[j][1] = fmaf(wv[j], pv.y, acc[j][1]);
                acc[j][2] = fmaf(wv[j], pv.z, acc[j][2]);
                acc[j][3] = fmaf(wv[j], pv.w, acc[j][3]);
            }
        }
    }
    __syncthreads();
    #pragma unroll
    for (int j = 0; j < 4; ++j)
        #pragma unroll
        for (int tt = 0; tt < 4; ++tt)
            qlds[(c4 + 64 * j) * 20 + th * 4 + tt] = fmaxf(acc[j][tt], 0.f);
    #pragma unroll
    for (int j = 0; j < 4; ++j) {
        float bv = be2[c4 + 64 * j];
        #pragma unroll
        for (int tt = 0; tt < 4; ++tt) acc[j][tt] = bv;
    }
    for (int kc = 0; kc < 16; ++kc) {
        const float4* wsrc = (const float4*)(We2 + (size_t)tid * 256 + kc * 16);
        float4 w0 = wsrc[0], w1 = wsrc[1], w2 = wsrc[2], w3 = wsrc[3];
        __syncthreads();
        wlds[0*256+tid]=w0.x; wlds[1*256+tid]=w0.y; wlds[2*256+tid]=w0.z; wlds[3*256+tid]=w0.w;
        wlds[4*256+tid]=w1.x; wlds[5*256+tid]=w1.y; wlds[6*256+tid]=w1.z; wlds[7*256+tid]=w1.w;
        wlds[8*256+tid]=w2.x; wlds[9*256+tid]=w2.y; wlds[10*256+tid]=w2.z; wlds[11*256+tid]=w2.w;
        wlds[12*256+tid]=w3.x; wlds[13*256+tid]=w3.y; wlds[14*256+tid]=w3.z; wlds[15*256+tid]=w3.w;
        __syncthreads();
        #pragma unroll
        for (int kk = 0; kk < 16; ++kk) {
            const float4 qv = *(const float4*)&qlds[(kc * 16 + kk) * 20 + th * 4];
            float wv[4];
            #pragma unroll
            for (int j = 0; j < 4; ++j) wv[j] = wlds[kk * 256 + c4 + 64 * j];
            #pragma unroll
            for (int j = 0; j < 4; ++j) {
                acc[j][0] = fmaf(wv[j], qv.x, acc[j][0]);
                acc[j][1] = fmaf(wv[j], qv.y, acc[j][1]);
                acc[j][2] = fmaf(wv[j], qv.z, acc[j][2]);
                acc[j][3] = fmaf(wv[j], qv.w, acc[j][3]);
            }
        }
    }
    #pragma unroll
    for (int tt = 0; tt < 4; ++tt) {
        size_t orow = ((size_t)b * T_ + t0 + th * 4 + tt) * 256;
        #pragma unroll
        for (int j = 0; j < 4; ++j)
            out[orow + c4 + 64 * j] = acc[j][tt];
    }
}

template <typename G>
static void run_pipeline_old(const float* y, const float* Wc, const float* bc,
                             const float* Wf, const float* bf, const float* Wr,
                             const float* br, const float* Ws, const float* bs,
                             const float* We1, const float* be1, const float* We2,
                             const float* be2, float* out, char* ws, hipStream_t stream)
{
    size_t xbytes = (size_t)B_ * RC_ * T_ * sizeof(float);
    float* xa = (float*)ws;
    float* xb = (float*)(ws + xbytes);
    G* g_all = (G*)(ws + 2 * xbytes);
    size_t gbytes = (size_t)NL_ * B_ * KH_ * T_ * sizeof(G);
    float* bsSum = (float*)(ws + 2 * xbytes + gbytes);
    bsum_kernel<<<1, 256, 0, stream>>>(bs, bsSum);
    init_conv_kernel<<<512, 256, 0, stream>>>(y, Wc, bc, xa);
    float* xin = xa; float* xout = xb;
    for (int i = 0; i < NL_; ++i) {
        int d = 1 << (i % 10);
        layer_kernel<G><<<512, 256, 0, stream>>>(
            xin, xout, g_all + (size_t)i * B_ * KH_ * T_,
            Wf + (size_t)i * RC_ * RC_ * 2, bf + (size_t)i * RC_,
            Wr + (size_t)i * RC_ * KH_, br + (size_t)i * RC_, d);
        float* tmp = xin; xin = xout; xout = tmp;
    }
    final_kernel<G><<<B_ * (T_ / 16), 256, 0, stream>>>(
        g_all, bsSum, Ws, We1, be1, We2, be2, out);
}

// ======================= host ==============================================
extern "C" void kernel_launch(void* const* d_in, const int* in_sizes, int n_in,
                              void* d_out, int out_size, void* d_ws, size_t ws_size,
                              hipStream_t stream)
{
    (void)in_sizes; (void)n_in; (void)out_size;
    const float* y   = (const float*)d_in[0];
    const float* Wc  = (const float*)d_in[1];
    const float* bc  = (const float*)d_in[2];
    const float* Wf  = (const float*)d_in[3];
    const float* bf  = (const float*)d_in[4];
    const float* Wr  = (const float*)d_in[5];
    const float* br  = (const float*)d_in[6];
    const float* Ws  = (const float*)d_in[7];
    const float* bs  = (const float*)d_in[8];
    const float* We1 = (const float*)d_in[9];
    const float* be1 = (const float*)d_in[10];
    const float* We2 = (const float*)d_in[11];
    const float* be2 = (const float*)d_in[12];
    float* out = (float*)d_out;
    char* ws = (char*)d_ws;

    size_t o = 0;
    auto alloc = [&](size_t bytes) { size_t r = o; o += (bytes + 1023) & ~(size_t)1023; return r; };
    size_t o_reg = alloc(NT_ * 512 * 2);       // y_t [NT][512]; later g [30][NT][16]
    size_t o_xa  = alloc(NT_ * 32 * 2);
    size_t o_xb  = alloc(NT_ * 32 * 2);
    size_t o_wcp = alloc(24576 * 2);
    size_t o_wfp = alloc(61440 * 2);
    size_t o_wrp = alloc(30720 * 2);
    size_t o_wst = alloc(122880 * 2);
    size_t o_we1 = alloc(65536 * 2);
    size_t o_we2 = alloc(65536 * 2);
    size_t o_bss = alloc(1024);
    size_t need_new = o;   // ~151.7 MB

    if (ws_size >= need_new) {
        ushort* y_t  = (ushort*)(ws + o_reg);
        ushort* g    = (ushort*)(ws + o_reg);   // overlays y_t after init
        ushort* xba  = (ushort*)(ws + o_xa);
        ushort* xbb  = (ushort*)(ws + o_xb);
        ushort* wcp  = (ushort*)(ws + o_wcp);
        ushort* wfp  = (ushort*)(ws + o_wfp);
        ushort* wrp  = (ushort*)(ws + o_wrp);
        ushort* wst  = (ushort*)(ws + o_wst);
        ushort* we1b = (ushort*)(ws + o_we1);
        ushort* we2b = (ushort*)(ws + o_we2);
        float*  bsSum= (float*)(ws + o_bss);

        prep_w_kernel<<<1448, 256, 0, stream>>>(Wc, Wf, Wr, Ws, We1, We2,
                                                wcp, wfp, wrp, wst, we1b, we2b);
        bsum_kernel<<<1, 256, 0, stream>>>(bs, bsSum);
        prep_y_kernel<<<2048, 256, 0, stream>>>(y, y_t);
        init_gemm_kernel<<<512, 256, 0, stream>>>(wcp, y_t, bc, xba);

        ushort* xbin = xba; ushort* xbout = xbb;
        for (int i = 0; i < NL_; ++i) {
            int d = 1 << (i % 10);
            layer_mfma_kernel<<<1024, 256, 0, stream>>>(
                xbin, xbout, g + (size_t)i * NT_ * 16,
                wfp + (size_t)i * 2048, wrp + (size_t)i * 1024,
                bf + i * 32, br + i * 32, d);
            ushort* tmp = xbin; xbin = xbout; xbout = tmp;
        }

        tail_kernel<<<2048, 256, 0, stream>>>(g, bsSum, wst, we1b, we2b,
                                              be1, be2, out);
        return;
    }

    size_t xbytes = (size_t)B_ * RC_ * T_ * sizeof(float);
    size_t need_f32 = 2 * xbytes + (size_t)NL_ * B_ * KH_ * T_ * 4 + 1024;
    if (ws_size >= need_f32)
        run_pipeline_old<float>(y, Wc, bc, Wf, bf, Wr, br, Ws, bs, We1, be1, We2, be2, out, ws, stream);
    else
        run_pipeline_old<__hip_bfloat16>(y, Wc, bc, Wf, bf, Wr, br, Ws, bs, We1, be1, We2, be2, out, ws, stream);
}

// Round 7
// 690.632 us; speedup vs baseline: 5.1710x; 1.0531x over previous
//
#include <hip/hip_runtime.h>
#include <hip/hip_bf16.h>

// WaveNet forward, MI355X — MFMA pipeline v3.
//  prep_w    : weights -> bf16 fragment-major layouts (tail A-frags direct-load)
//  prep_y    : y [b][256][T] fp32 -> y_t [t'][512] bf16 {hi|lo}
//  init_gemm : x0 = Wc@y + bc, K=768 = [hi|hi|lo]@[yh|yl|yh]
//  layer x30 : h=Wf·{x[t-d],x[t]} (MFMA), gates (VALU), r=Wr·g (MFMA), residual
//  tail v3   : fused skip(480)->relu->e1->relu->e2->transpose.
//              A-frags global-direct (L2), B-frags reg->LDS frag-major 4KB dbuf,
//              p/q frag-major 32KB aliased. 19 barriers, ~0 bank conflicts.

#define B_ 4
#define T_ 32768
#define RC_ 32
#define KH_ 16
#define SC_ 256
#define CLASSES_ 256
#define NL_ 30
#define NT_ 131072L   // B_*T_

using f32x4 = __attribute__((ext_vector_type(4))) float;
using s16x8 = __attribute__((ext_vector_type(8))) short;

__device__ inline float fast_rcp(float x) { return __builtin_amdgcn_rcpf(x); }
__device__ inline float fast_sigmoid(float x) { return fast_rcp(1.f + __expf(-x)); }
__device__ inline float fast_tanh(float x) { return 1.f - 2.f * fast_rcp(__expf(2.f * x) + 1.f); }

__device__ inline ushort f2bf(float v) {
    __hip_bfloat16 h = __float2bfloat16(v);
    return __builtin_bit_cast(ushort, h);
}
__device__ inline uint pack2(float a, float b) {
    return (uint)f2bf(a) | ((uint)f2bf(b) << 16);
}
__device__ inline float bflo(uint u) { return __builtin_bit_cast(float, u << 16); }
__device__ inline float bfhi(uint u) { return __builtin_bit_cast(float, u & 0xffff0000u); }
__device__ inline s16x8 mfma_in(uint4 u) { return __builtin_bit_cast(s16x8, u); }

// ======================= prep: weights =====================================
// regions: wcp 24576 | wfp 61440 | wrp 30720 | wsF 122880 | we1F 65536 | we2F 65536
// wsF  [15 kc][16 mrow][64 lane][8 j]: A-frag for skip GEMM (m=mrow*16+(lane&15),
//      k=kc*32+(lane>>4)*8+j; Ws k-index = layer*16+ci)
// weXF [8 kc][16 mrow][64 lane][8 j]: A-frag for e1/e2 (row-major [256][256] src)
__global__ __launch_bounds__(256) void prep_w_kernel(
    const float* __restrict__ Wc, const float* __restrict__ Wf,
    const float* __restrict__ Wr, const float* __restrict__ Ws,
    const float* __restrict__ We1, const float* __restrict__ We2,
    ushort* __restrict__ wcp, ushort* __restrict__ wfp, ushort* __restrict__ wrp,
    ushort* __restrict__ wsF, ushort* __restrict__ we1F, ushort* __restrict__ we2F)
{
    int j = blockIdx.x * 256 + threadIdx.x;
    if (j < 24576) {                       // WcP[32][768] = [hi | hi | lo]
        int m = j / 768, k = j % 768;
        float v = Wc[m * 256 + (k & 255)];
        if (k < 512) wcp[j] = f2bf(v);
        else {
            float hi = __bfloat162float(__float2bfloat16(v));
            wcp[j] = f2bf(v - hi);
        }
    } else if (j < 86016) {                // WfP[30][2][32][32]  (tap, out c, in ci)
        int e = j - 24576;
        int i = e >> 11; int r = e & 2047;
        int tap = r >> 10, c = (r >> 5) & 31, ci = r & 31;
        wfp[e] = f2bf(Wf[((size_t)(i * 32 + c) * 32 + ci) * 2 + tap]);
    } else if (j < 116736) {               // WrP[30][32][32] zero-padded k>=16
        int e = j - 86016;
        int i = e >> 10; int c = (e >> 5) & 31; int k = e & 31;
        wrp[e] = (k < 16) ? f2bf(Wr[(size_t)(i * 32 + c) * 16 + k]) : (ushort)0;
    } else if (j < 239616) {               // wsF fragment-major
        int e = j - 116736;
        int jj = e & 7, lane = (e >> 3) & 63, mrow = (e >> 9) & 15, kc = e >> 13;
        int m = mrow * 16 + (lane & 15);
        int k = kc * 32 + (lane >> 4) * 8 + jj;      // 0..479
        int i = k >> 4, ci = k & 15;
        wsF[e] = f2bf(Ws[((size_t)i * 256 + m) * 16 + ci]);
    } else if (j < 305152) {               // we1F fragment-major
        int e = j - 239616;
        int jj = e & 7, lane = (e >> 3) & 63, mrow = (e >> 9) & 15, kc = e >> 13;
        int m = mrow * 16 + (lane & 15);
        int k = kc * 32 + (lane >> 4) * 8 + jj;
        we1F[e] = f2bf(We1[m * 256 + k]);
    } else if (j < 370688) {               // we2F fragment-major
        int e = j - 305152;
        int jj = e & 7, lane = (e >> 3) & 63, mrow = (e >> 9) & 15, kc = e >> 13;
        int m = mrow * 16 + (lane & 15);
        int k = kc * 32 + (lane >> 4) * 8 + jj;
        we2F[e] = f2bf(We2[m * 256 + k]);
    }
}

__global__ void bsum_kernel(const float* __restrict__ bs, float* __restrict__ bsSum) {
    int s = threadIdx.x;
    float v = 0.f;
    #pragma unroll
    for (int i = 0; i < NL_; ++i) v += bs[i * SC_ + s];
    bsSum[s] = v;
}

// ======================= prep: y transpose + hi/lo split ===================
__global__ __launch_bounds__(256) void prep_y_kernel(
    const float* __restrict__ y, ushort* __restrict__ y_t)
{
    __shared__ float lds[32][65];
    int tid = threadIdx.x;
    int b = blockIdx.x >> 9;
    long t0 = (long)(blockIdx.x & 511) * 64;
    for (int cc = 0; cc < 8; ++cc) {
        int c = cc * 32 + (tid >> 3);
        int tp = (tid & 7) * 8;
        const float* src = y + ((size_t)b * 256 + c) * T_ + t0 + tp;
        float4 v0 = *(const float4*)src;
        float4 v1 = *(const float4*)(src + 4);
        lds[tid >> 3][tp + 0] = v0.x; lds[tid >> 3][tp + 1] = v0.y;
        lds[tid >> 3][tp + 2] = v0.z; lds[tid >> 3][tp + 3] = v0.w;
        lds[tid >> 3][tp + 4] = v1.x; lds[tid >> 3][tp + 5] = v1.y;
        lds[tid >> 3][tp + 6] = v1.z; lds[tid >> 3][tp + 7] = v1.w;
        __syncthreads();
        int t = tid & 63, cp = tid >> 6;
        float v[8];
        #pragma unroll
        for (int jj = 0; jj < 8; ++jj) v[jj] = lds[cp * 8 + jj][t];
        uint hi[4], lo[4];
        #pragma unroll
        for (int jj = 0; jj < 4; ++jj) {
            float a = v[2 * jj], bv = v[2 * jj + 1];
            float ah = __bfloat162float(__float2bfloat16(a));
            float bh = __bfloat162float(__float2bfloat16(bv));
            hi[jj] = pack2(a, bv);
            lo[jj] = pack2(a - ah, bv - bh);
        }
        ushort* dst = y_t + ((size_t)b * T_ + t0 + t) * 512 + cc * 32 + cp * 8;
        *(uint4*)dst = make_uint4(hi[0], hi[1], hi[2], hi[3]);
        *(uint4*)(dst + 256) = make_uint4(lo[0], lo[1], lo[2], lo[3]);
        __syncthreads();
    }
}

// ======================= init GEMM: x0 = Wc@y + bc =========================
__global__ __launch_bounds__(256) void init_gemm_kernel(
    const ushort* __restrict__ wcp, const ushort* __restrict__ y_t,
    const float* __restrict__ bc, ushort* __restrict__ x0)
{
    __shared__ ushort sa[2][32 * 40];
    __shared__ ushort sb[2][256 * 40];
    int tid = threadIdx.x;
    int wid = tid >> 6, lane = tid & 63, q = lane >> 4, ln = lane & 15;
    long n0 = (long)blockIdx.x * 256;

    uint4 ar0, ar1, br0, br1, br2, br3;
    auto load_tile = [&](int kc) {
        int k0 = kc * 32;
        int koff = (k0 < 512) ? k0 : k0 - 512;
        if (tid < 64) {
            int m = tid >> 1, h = tid & 1;
            const uint4* s = (const uint4*)(wcp + m * 768 + k0 + h * 16);
            ar0 = s[0]; ar1 = s[1];
        }
        const uint4* sB = (const uint4*)(y_t + (n0 + tid) * 512 + koff);
        br0 = sB[0]; br1 = sB[1]; br2 = sB[2]; br3 = sB[3];
    };
    auto store_tile = [&](int buf) {
        if (tid < 64) {
            int m = tid >> 1, h = tid & 1;
            *(uint4*)&sa[buf][m * 40 + h * 16] = ar0;
            *(uint4*)&sa[buf][m * 40 + h * 16 + 8] = ar1;
        }
        *(uint4*)&sb[buf][tid * 40 + 0]  = br0;
        *(uint4*)&sb[buf][tid * 40 + 8]  = br1;
        *(uint4*)&sb[buf][tid * 40 + 16] = br2;
        *(uint4*)&sb[buf][tid * 40 + 24] = br3;
    };

    f32x4 acc[2][4];
    #pragma unroll
    for (int mi = 0; mi < 2; ++mi) {
        f32x4 bv = *(const f32x4*)&bc[mi * 16 + 4 * q];
        #pragma unroll
        for (int ni = 0; ni < 4; ++ni) acc[mi][ni] = bv;
    }
    load_tile(0);
    for (int kc = 0; kc < 24; ++kc) {
        int buf = kc & 1;
        store_tile(buf);
        __syncthreads();
        if (kc + 1 < 24) load_tile(kc + 1);
        s16x8 af[2];
        #pragma unroll
        for (int mi = 0; mi < 2; ++mi)
            af[mi] = mfma_in(*(const uint4*)&sa[buf][(mi * 16 + ln) * 40 + q * 8]);
        #pragma unroll
        for (int ni = 0; ni < 4; ++ni) {
            s16x8 bfr = mfma_in(*(const uint4*)&sb[buf][(wid * 64 + ni * 16 + ln) * 40 + q * 8]);
            #pragma unroll
            for (int mi = 0; mi < 2; ++mi)
                acc[mi][ni] = __builtin_amdgcn_mfma_f32_16x16x32_bf16(af[mi], bfr, acc[mi][ni], 0, 0, 0);
        }
        __syncthreads();
    }
    #pragma unroll
    for (int mi = 0; mi < 2; ++mi) {
        int ch = mi * 16 + 4 * q;
        #pragma unroll
        for (int ni = 0; ni < 4; ++ni) {
            long t = n0 + wid * 64 + ni * 16 + ln;
            f32x4 v = acc[mi][ni];
            uint2 pk; pk.x = pack2(v[0], v[1]); pk.y = pack2(v[2], v[3]);
            *(uint2*)&x0[t * 32 + ch] = pk;
        }
    }
}

// ======================= layer (MFMA, bf16 x) ==============================
__global__ __launch_bounds__(256) void layer_mfma_kernel(
    const ushort* __restrict__ xb_in, ushort* __restrict__ xb_out,
    ushort* __restrict__ g_out,
    const ushort* __restrict__ wfp, const ushort* __restrict__ wrp,
    const float* __restrict__ bfp, const float* __restrict__ brp, int d)
{
    int tid = threadIdx.x;
    int wid = tid >> 6, lane = tid & 63, q = lane >> 4, ln = lane & 15;
    long tw = (long)blockIdx.x * 128 + wid * 32;

    s16x8 wfA[2][2], wrA[2];
    #pragma unroll
    for (int mb = 0; mb < 2; ++mb) {
        #pragma unroll
        for (int tap = 0; tap < 2; ++tap)
            wfA[mb][tap] = mfma_in(*(const uint4*)&wfp[(tap * 32 + mb * 16 + ln) * 32 + q * 8]);
        wrA[mb] = mfma_in(*(const uint4*)&wrp[(mb * 16 + ln) * 32 + q * 8]);
    }
    f32x4 bfv0 = *(const f32x4*)&bfp[4 * q];
    f32x4 bfv1 = *(const f32x4*)&bfp[16 + 4 * q];
    f32x4 brv0 = *(const f32x4*)&brp[4 * q];
    f32x4 brv1 = *(const f32x4*)&brp[16 + 4 * q];
    const float inv_s2 = 0.70710678118654752f;

    #pragma unroll
    for (int nb = 0; nb < 2; ++nb) {
        long t = tw + nb * 16 + ln;
        bool vok = ((int)(t & (T_ - 1)) >= d);
        long r0 = vok ? (t - d) : t;
        uint4 u0 = *(const uint4*)&xb_in[r0 * 32 + 8 * q];
        if (!vok) u0 = make_uint4(0, 0, 0, 0);
        uint4 u1 = *(const uint4*)&xb_in[t * 32 + 8 * q];
        s16x8 b0 = mfma_in(u0), b1 = mfma_in(u1);

        f32x4 h0 = {}, h1 = {};
        h0 = __builtin_amdgcn_mfma_f32_16x16x32_bf16(wfA[0][0], b0, h0, 0, 0, 0);
        h0 = __builtin_amdgcn_mfma_f32_16x16x32_bf16(wfA[0][1], b1, h0, 0, 0, 0);
        h1 = __builtin_amdgcn_mfma_f32_16x16x32_bf16(wfA[1][0], b0, h1, 0, 0, 0);
        h1 = __builtin_amdgcn_mfma_f32_16x16x32_bf16(wfA[1][1], b1, h1, 0, 0, 0);

        float g[4];
        #pragma unroll
        for (int r = 0; r < 4; ++r)
            g[r] = fast_tanh(h0[r] + bfv0[r]) * fast_sigmoid(h1[r] + bfv1[r]);
        uint p01 = pack2(g[0], g[1]), p23 = pack2(g[2], g[3]);
        uint2 gst; gst.x = p01; gst.y = p23;
        *(uint2*)&g_out[t * 16 + 4 * q] = gst;

        // redistribute C-layout g (ch 4q+r @ t=ln) -> B-fragment (ch 8q+j @ t=ln)
        int sA = q * 32 + ln;   // >=64 wraps; those feed zero-padded Wr rows
        uint f0 = (uint)__shfl((int)p01, sA);
        uint f1 = (uint)__shfl((int)p23, sA);
        uint f2 = (uint)__shfl((int)p01, sA + 16);
        uint f3 = (uint)__shfl((int)p23, sA + 16);
        s16x8 gb = mfma_in(make_uint4(f0, f1, f2, f3));

        f32x4 rr0 = {}, rr1 = {};
        rr0 = __builtin_amdgcn_mfma_f32_16x16x32_bf16(wrA[0], gb, rr0, 0, 0, 0);
        rr1 = __builtin_amdgcn_mfma_f32_16x16x32_bf16(wrA[1], gb, rr1, 0, 0, 0);

        uint2 xr0 = *(const uint2*)&xb_in[t * 32 + 4 * q];
        uint2 xr1 = *(const uint2*)&xb_in[t * 32 + 16 + 4 * q];
        float o00 = (rr0[0] + brv0[0] + bflo(xr0.x)) * inv_s2;
        float o01 = (rr0[1] + brv0[1] + bfhi(xr0.x)) * inv_s2;
        float o02 = (rr0[2] + brv0[2] + bflo(xr0.y)) * inv_s2;
        float o03 = (rr0[3] + brv0[3] + bfhi(xr0.y)) * inv_s2;
        float o10 = (rr1[0] + brv1[0] + bflo(xr1.x)) * inv_s2;
        float o11 = (rr1[1] + brv1[1] + bfhi(xr1.x)) * inv_s2;
        float o12 = (rr1[2] + brv1[2] + bflo(xr1.y)) * inv_s2;
        float o13 = (rr1[3] + brv1[3] + bfhi(xr1.y)) * inv_s2;
        uint2 xp0; xp0.x = pack2(o00, o01); xp0.y = pack2(o02, o03);
        uint2 xp1; xp1.x = pack2(o10, o11); xp1.y = pack2(o12, o13);
        *(uint2*)&xb_out[t * 32 + 4 * q] = xp0;
        *(uint2*)&xb_out[t * 32 + 16 + 4 * q] = xp1;
    }
}

// ======================= fused tail v3 =====================================
// 64 t per block, 256 ch. A-frags direct from global (L2-resident frag-major).
// B(g) staged reg->LDS frag-major, 4KB double-buffer, 1 barrier/kc.
// p/q frag-major in 32KB LDS, q aliased over p. 40KB LDS -> 4 blocks/CU.
__global__ __launch_bounds__(256, 4) void tail_kernel(
    const ushort* __restrict__ g_all, const float* __restrict__ bsSum,
    const ushort* __restrict__ wsF, const ushort* __restrict__ we1F,
    const ushort* __restrict__ we2F, const float* __restrict__ be1,
    const float* __restrict__ be2, float* __restrict__ out)
{
    __shared__ ushort stg[2][2048];   // B-frag staging [4 ni][64 lane][8]
    __shared__ ushort pq[16384];      // p/q frags [8 kc][4 ni][64 lane][8]
    int tid = threadIdx.x;
    int wid = tid >> 6, lane = tid & 63, q = lane >> 4, ln = lane & 15;
    long n0 = (long)blockIdx.x * 64;
    int wrow = wid * 64;

    // staging map: thread (sn, sip, shalf) loads g[(2kc+sip)][n0+sn][shalf*8..+8]
    // -> frag dest (ni=sn>>4, q'=sip*2+shalf, ln'=sn&15)
    int sn = tid & 63, sip = (tid >> 6) & 1, shalf = tid >> 7;
    int sdst = ((sn >> 4) * 64 + (sip * 2 + shalf) * 16 + (sn & 15)) * 8;

    f32x4 acc[4][4];
    #pragma unroll
    for (int mi = 0; mi < 4; ++mi) {
        f32x4 bv = *(const f32x4*)&bsSum[wrow + mi * 16 + 4 * q];
        #pragma unroll
        for (int ni = 0; ni < 4; ++ni) acc[mi][ni] = bv;
    }

    // ---------- phase 1: skip (K=480, 15 k-chunks) ----------
    uint4 ld = *(const uint4*)(g_all + ((size_t)sip * NT_ + n0 + sn) * 16 + shalf * 8);
    *(uint4*)&stg[0][sdst] = ld;
    for (int kc = 0; kc < 15; ++kc) {
        __syncthreads();
        if (kc < 14)
            ld = *(const uint4*)(g_all +
                ((size_t)(2 * (kc + 1) + sip) * NT_ + n0 + sn) * 16 + shalf * 8);
        s16x8 af[4], bfr[4];
        #pragma unroll
        for (int mi = 0; mi < 4; ++mi)
            af[mi] = mfma_in(*(const uint4*)(wsF +
                (((size_t)kc * 16 + wid * 4 + mi) * 64 + lane) * 8));
        #pragma unroll
        for (int ni = 0; ni < 4; ++ni)
            bfr[ni] = mfma_in(*(const uint4*)&stg[kc & 1][(ni * 64 + lane) * 8]);
        #pragma unroll
        for (int ni = 0; ni < 4; ++ni)
            #pragma unroll
            for (int mi = 0; mi < 4; ++mi)
                acc[mi][ni] = __builtin_amdgcn_mfma_f32_16x16x32_bf16(
                    af[mi], bfr[ni], acc[mi][ni], 0, 0, 0);
        if (kc < 14) *(uint4*)&stg[(kc + 1) & 1][sdst] = ld;
    }
    // p -> pq (frag-major): dest((ch>>5)*4+ni, lane'=((ch&31)>>3)*16+ln, j=ch&7)
    #pragma unroll
    for (int mi = 0; mi < 4; ++mi) {
        int ch = wrow + mi * 16 + 4 * q;
        int dbase = ((ch >> 5) * 4) * 512 + (((ch & 31) >> 3) * 16 + ln) * 8 + (ch & 7);
        #pragma unroll
        for (int ni = 0; ni < 4; ++ni) {
            f32x4 v = acc[mi][ni];
            uint2 pk;
            pk.x = pack2(fmaxf(v[0], 0.f), fmaxf(v[1], 0.f));
            pk.y = pack2(fmaxf(v[2], 0.f), fmaxf(v[3], 0.f));
            *(uint2*)&pq[dbase + ni * 512] = pk;
        }
    }
    __syncthreads();   // p visible to all

    // ---------- phase 2: e1 (K=256, no in-loop barriers) ----------
    #pragma unroll
    for (int mi = 0; mi < 4; ++mi) {
        f32x4 bv = *(const f32x4*)&be1[wrow + mi * 16 + 4 * q];
        #pragma unroll
        for (int ni = 0; ni < 4; ++ni) acc[mi][ni] = bv;
    }
    for (int kc = 0; kc < 8; ++kc) {
        s16x8 af[4], bfr[4];
        #pragma unroll
        for (int mi = 0; mi < 4; ++mi)
            af[mi] = mfma_in(*(const uint4*)(we1F +
                (((size_t)kc * 16 + wid * 4 + mi) * 64 + lane) * 8));
        #pragma unroll
        for (int ni = 0; ni < 4; ++ni)
            bfr[ni] = mfma_in(*(const uint4*)&pq[(kc * 4 + ni) * 512 + lane * 8]);
        #pragma unroll
        for (int ni = 0; ni < 4; ++ni)
            #pragma unroll
            for (int mi = 0; mi < 4; ++mi)
                acc[mi][ni] = __builtin_amdgcn_mfma_f32_16x16x32_bf16(
                    af[mi], bfr[ni], acc[mi][ni], 0, 0, 0);
    }
    __syncthreads();   // all p reads done; q may overwrite
    #pragma unroll
    for (int mi = 0; mi < 4; ++mi) {
        int ch = wrow + mi * 16 + 4 * q;
        int dbase = ((ch >> 5) * 4) * 512 + (((ch & 31) >> 3) * 16 + ln) * 8 + (ch & 7);
        #pragma unroll
        for (int ni = 0; ni < 4; ++ni) {
            f32x4 v = acc[mi][ni];
            uint2 pk;
            pk.x = pack2(fmaxf(v[0], 0.f), fmaxf(v[1], 0.f));
            pk.y = pack2(fmaxf(v[2], 0.f), fmaxf(v[3], 0.f));
            *(uint2*)&pq[dbase + ni * 512] = pk;
        }
    }
    __syncthreads();   // q visible

    // ---------- phase 3: e2 ----------
    #pragma unroll
    for (int mi = 0; mi < 4; ++mi) {
        f32x4 bv = *(const f32x4*)&be2[wrow + mi * 16 + 4 * q];
        #pragma unroll
        for (int ni = 0; ni < 4; ++ni) acc[mi][ni] = bv;
    }
    for (int kc = 0; kc < 8; ++kc) {
        s16x8 af[4], bfr[4];
        #pragma unroll
        for (int mi = 0; mi < 4; ++mi)
            af[mi] = mfma_in(*(const uint4*)(we2F +
                (((size_t)kc * 16 + wid * 4 + mi) * 64 + lane) * 8));
        #pragma unroll
        for (int ni = 0; ni < 4; ++ni)
            bfr[ni] = mfma_in(*(const uint4*)&pq[(kc * 4 + ni) * 512 + lane * 8]);
        #pragma unroll
        for (int ni = 0; ni < 4; ++ni)
            #pragma unroll
            for (int mi = 0; mi < 4; ++mi)
                acc[mi][ni] = __builtin_amdgcn_mfma_f32_16x16x32_bf16(
                    af[mi], bfr[ni], acc[mi][ni], 0, 0, 0);
    }
    #pragma unroll
    for (int mi = 0; mi < 4; ++mi) {
        int ch = wrow + mi * 16 + 4 * q;
        #pragma unroll
        for (int ni = 0; ni < 4; ++ni) {
            long t = n0 + ni * 16 + ln;
            *(f32x4*)&out[t * 256 + ch] = acc[mi][ni];
        }
    }
}

// ======================= OLD fallback pipeline (round-2, passing) ==========
__device__ inline float load_g(const float* p) { return *p; }
__device__ inline float load_g(const __hip_bfloat16* p) { return __bfloat162float(*p); }
__device__ inline void store_g(float* p, float v) { *p = v; }
__device__ inline void store_g(__hip_bfloat16* p, float v) { *p = __float2bfloat16(v); }

__global__ __launch_bounds__(256) void init_conv_kernel(
    const float* __restrict__ y, const float* __restrict__ Wc,
    const float* __restrict__ bc, float* __restrict__ x0)
{
    int gid = blockIdx.x * 256 + threadIdx.x;
    int b = gid >> 15;
    int t = gid & (T_ - 1);
    float acc[RC_];
    #pragma unroll
    for (int c = 0; c < RC_; ++c) acc[c] = bc[c];
    const float* yb = y + (size_t)b * CLASSES_ * T_ + t;
    for (int cb = 0; cb < CLASSES_; cb += 32) {
        float yv[32];
        #pragma unroll
        for (int j = 0; j < 32; ++j) yv[j] = yb[(size_t)(cb + j) * T_];
        #pragma unroll
        for (int c = 0; c < RC_; ++c)
            #pragma unroll
            for (int j = 0; j < 32; ++j)
                acc[c] = fmaf(Wc[c * CLASSES_ + cb + j], yv[j], acc[c]);
    }
    float* xo = x0 + (size_t)b * RC_ * T_ + t;
    #pragma unroll
    for (int c = 0; c < RC_; ++c) xo[(size_t)c * T_] = acc[c];
}

template <typename G>
__global__ __launch_bounds__(256) void layer_kernel(
    const float* __restrict__ x_in, float* __restrict__ x_out, G* __restrict__ g_out,
    const float* __restrict__ wf, const float* __restrict__ bfp,
    const float* __restrict__ wr, const float* __restrict__ brp, int d)
{
    int gid = blockIdx.x * 256 + threadIdx.x;
    int b = gid >> 15;
    int t = gid & (T_ - 1);
    const float* xbase = x_in + (size_t)b * RC_ * T_ + t;
    float xm[RC_], xd[RC_];
    #pragma unroll
    for (int ci = 0; ci < RC_; ++ci) xm[ci] = xbase[(size_t)ci * T_];
    #pragma unroll
    for (int ci = 0; ci < RC_; ++ci)
        xd[ci] = (t >= d) ? xbase[(size_t)ci * T_ - d] : 0.f;
    float a_[KH_];
    #pragma unroll
    for (int c = 0; c < KH_; ++c) {
        float s = bfp[c];
        #pragma unroll
        for (int ci = 0; ci < RC_; ++ci) {
            s = fmaf(wf[(c * RC_ + ci) * 2 + 0], xd[ci], s);
            s = fmaf(wf[(c * RC_ + ci) * 2 + 1], xm[ci], s);
        }
        a_[c] = s;
    }
    float g[KH_];
    #pragma unroll
    for (int c = 0; c < KH_; ++c) {
        float s = bfp[KH_ + c];
        #pragma unroll
        for (int ci = 0; ci < RC_; ++ci) {
            s = fmaf(wf[((KH_ + c) * RC_ + ci) * 2 + 0], xd[ci], s);
            s = fmaf(wf[((KH_ + c) * RC_ + ci) * 2 + 1], xm[ci], s);
        }
        g[c] = fast_tanh(a_[c]) * fast_sigmoid(s);
    }
    G* gb = g_out + (size_t)b * KH_ * T_ + t;
    #pragma unroll
    for (int c = 0; c < KH_; ++c) store_g(gb + (size_t)c * T_, g[c]);
    float* xo = x_out + (size_t)b * RC_ * T_ + t;
    #pragma unroll
    for (int c = 0; c < RC_; ++c) {
        float s = brp[c];
        #pragma unroll
        for (int ci = 0; ci < KH_; ++ci) s = fmaf(wr[c * KH_ + ci], g[ci], s);
        xo[(size_t)c * T_] = (s + xm[c]) * 0.70710678118654752f;
    }
}

template <typename G>
__global__ __launch_bounds__(256) void final_kernel(
    const G* __restrict__ g_all, const float* __restrict__ bsSum,
    const float* __restrict__ Ws, const float* __restrict__ We1,
    const float* __restrict__ be1, const float* __restrict__ We2,
    const float* __restrict__ be2, float* __restrict__ out)
{
    __shared__ float smem[14336];
    float* plds = smem;
    float* qlds = smem + 5120;
    float* glds = smem;
    float* wlds = smem + 10240;
    int tid = threadIdx.x;
    int bt = blockIdx.x;
    int b = bt >> 11;
    int t0 = (bt & 2047) << 4;
    int c4 = tid & 63;
    int th = tid >> 6;
    for (int e = tid; e < 480 * 16; e += 256) {
        int row = e >> 4, col = e & 15;
        int i = row >> 4, ci = row & 15;
        glds[e] = load_g(g_all + ((size_t)(i * B_ + b) * KH_ + ci) * T_ + t0 + col);
    }
    __syncthreads();
    float acc[4][4];
    #pragma unroll
    for (int j = 0; j < 4; ++j) {
        float bv = bsSum[c4 + 64 * j];
        #pragma unroll
        for (int tt = 0; tt < 4; ++tt) acc[j][tt] = bv;
    }
    for (int i = 0; i < NL_; ++i) {
        const float4* wsrc = (const float4*)(Ws + ((size_t)i * 256 + tid) * 16);
        float4 w0 = wsrc[0], w1 = wsrc[1], w2 = wsrc[2], w3 = wsrc[3];
        __syncthreads();
        wlds[0*256+tid]=w0.x; wlds[1*256+tid]=w0.y; wlds[2*256+tid]=w0.z; wlds[3*256+tid]=w0.w;
        wlds[4*256+tid]=w1.x; wlds[5*256+tid]=w1.y; wlds[6*256+tid]=w1.z; wlds[7*256+tid]=w1.w;
        wlds[8*256+tid]=w2.x; wlds[9*256+tid]=w2.y; wlds[10*256+tid]=w2.z; wlds[11*256+tid]=w2.w;
        wlds[12*256+tid]=w3.x; wlds[13*256+tid]=w3.y; wlds[14*256+tid]=w3.z; wlds[15*256+tid]=w3.w;
        __syncthreads();
        #pragma unroll
        for (int ci = 0; ci < 16; ++ci) {
            const float4 gv = *(const float4*)&glds[(i * 16 + ci) * 16 + th * 4];
            float wv[4];
            #pragma unroll
            for (int j = 0; j < 4; ++j) wv[j] = wlds[ci * 256 + c4 + 64 * j];
            #pragma unroll
            for (int j = 0; j < 4; ++j) {
                acc[j][0] = fmaf(wv[j], gv.x, acc[j][0]);
                acc[j][1] = fmaf(wv[j], gv.y, acc[j][1]);
                acc[j][2] = fmaf(wv[j], gv.z, acc[j][2]);
                acc[j][3] = fmaf(wv[j], gv.w, acc[j][3]);
            }
        }
    }
    __syncthreads();
    #pragma unroll
    for (int j = 0; j < 4; ++j)
        #pragma unroll
        for (int tt = 0; tt < 4; ++tt)
            plds[(c4 + 64 * j) * 20 + th * 4 + tt] = fmaxf(acc[j][tt], 0.f);
    #pragma unroll
    for (int j = 0; j < 4; ++j) {
        float bv = be1[c4 + 64 * j];
        #pragma unroll
        for (int tt = 0; tt < 4; ++tt) acc[j][tt] = bv;
    }
    for (int kc = 0; kc < 16; ++kc) {
        const float4* wsrc = (const float4*)(We1 + (size_t)tid * 256 + kc * 16);
        float4 w0 = wsrc[0], w1 = wsrc[1], w2 = wsrc[2], w3 = wsrc[3];
        __syncthreads();
        wlds[0*256+tid]=w0.x; wlds[1*256+tid]=w0.y; wlds[2*256+tid]=w0.z; wlds[3*256+tid]=w0.w;
        wlds[4*256+tid]=w1.x; wlds[5*256+tid]=w1.y; wlds[6*256+tid]=w1.z; wlds[7*256+tid]=w1.w;
        wlds[8*256+tid]=w2.x; wlds[9*256+tid]=w2.y; wlds[10*256+tid]=w2.z; wlds[11*256+tid]=w2.w;
        wlds[12*256+tid]=w3.x; wlds[13*256+tid]=w3.y; wlds[14*256+tid]=w3.z; wlds[15*256+tid]=w3.w;
        __syncthreads();
        #pragma unroll
        for (int kk = 0; kk < 16; ++kk) {
            const float4 pv = *(const float4*)&plds[(kc * 16 + kk) * 20 + th * 4];
            float wv[4];
            #pragma unroll
            for (int j = 0; j < 4; ++j) wv[j] = wlds[kk * 256 + c4 + 64 * j];
            #pragma unroll
            for (int j = 0; j < 4; ++j) {
                acc[j][0] = fmaf(wv[j], pv.x, acc[j][0]);
                acc[j][1] = fmaf(wv[j], pv.y, acc[j][1]);
                acc[j][2] = fmaf(wv[j], pv.z, acc[j][2]);
                acc[j][3] = fmaf(wv[j], pv.w, acc[j][3]);
            }
        }
    }
    __syncthreads();
    #pragma unroll
    for (int j = 0; j < 4; ++j)
        #pragma unroll
        for (int tt = 0; tt < 4; ++tt)
            qlds[(c4 + 64 * j) * 20 + th * 4 + tt] = fmaxf(acc[j][tt], 0.f);
    #pragma unroll
    for (int j = 0; j < 4; ++j) {
        float bv = be2[c4 + 64 * j];
        #pragma unroll
        for (int tt = 0; tt < 4; ++tt) acc[j][tt] = bv;
    }
    for (int kc = 0; kc < 16; ++kc) {
        const float4* wsrc = (const float4*)(We2 + (size_t)tid * 256 + kc * 16);
        float4 w0 = wsrc[0], w1 = wsrc[1], w2 = wsrc[2], w3 = wsrc[3];
        __syncthreads();
        wlds[0*256+tid]=w0.x; wlds[1*256+tid]=w0.y; wlds[2*256+tid]=w0.z; wlds[3*256+tid]=w0.w;
        wlds[4*256+tid]=w1.x; wlds[5*256+tid]=w1.y; wlds[6*256+tid]=w1.z; wlds[7*256+tid]=w1.w;
        wlds[8*256+tid]=w2.x; wlds[9*256+tid]=w2.y; wlds[10*256+tid]=w2.z; wlds[11*256+tid]=w2.w;
        wlds[12*256+tid]=w3.x; wlds[13*256+tid]=w3.y; wlds[14*256+tid]=w3.z; wlds[15*256+tid]=w3.w;
        __syncthreads();
        #pragma unroll
        for (int kk = 0; kk < 16; ++kk) {
            const float4 qv = *(const float4*)&qlds[(kc * 16 + kk) * 20 + th * 4];
            float wv[4];
            #pragma unroll
            for (int j = 0; j < 4; ++j) wv[j] = wlds[kk * 256 + c4 + 64 * j];
            #pragma unroll
            for (int j = 0; j < 4; ++j) {
                acc[j][0] = fmaf(wv[j], qv.x, acc[j][0]);
                acc[j][1] = fmaf(wv[j], qv.y, acc[j][1]);
                acc[j][2] = fmaf(wv[j], qv.z, acc[j][2]);
                acc[j][3] = fmaf(wv[j], qv.w, acc[j][3]);
            }
        }
    }
    #pragma unroll
    for (int tt = 0; tt < 4; ++tt) {
        size_t orow = ((size_t)b * T_ + t0 + th * 4 + tt) * 256;
        #pragma unroll
        for (int j = 0; j < 4; ++j)
            out[orow + c4 + 64 * j] = acc[j][tt];
    }
}

template <typename G>
static void run_pipeline_old(const float* y, const float* Wc, const float* bc,
                             const float* Wf, const float* bf, const float* Wr,
                             const float* br, const float* Ws, const float* bs,
                             const float* We1, const float* be1, const float* We2,
                             const float* be2, float* out, char* ws, hipStream_t stream)
{
    size_t xbytes = (size_t)B_ * RC_ * T_ * sizeof(float);
    float* xa = (float*)ws;
    float* xb = (float*)(ws + xbytes);
    G* g_all = (G*)(ws + 2 * xbytes);
    size_t gbytes = (size_t)NL_ * B_ * KH_ * T_ * sizeof(G);
    float* bsSum = (float*)(ws + 2 * xbytes + gbytes);
    bsum_kernel<<<1, 256, 0, stream>>>(bs, bsSum);
    init_conv_kernel<<<512, 256, 0, stream>>>(y, Wc, bc, xa);
    float* xin = xa; float* xout = xb;
    for (int i = 0; i < NL_; ++i) {
        int d = 1 << (i % 10);
        layer_kernel<G><<<512, 256, 0, stream>>>(
            xin, xout, g_all + (size_t)i * B_ * KH_ * T_,
            Wf + (size_t)i * RC_ * RC_ * 2, bf + (size_t)i * RC_,
            Wr + (size_t)i * RC_ * KH_, br + (size_t)i * RC_, d);
        float* tmp = xin; xin = xout; xout = tmp;
    }
    final_kernel<G><<<B_ * (T_ / 16), 256, 0, stream>>>(
        g_all, bsSum, Ws, We1, be1, We2, be2, out);
}

// ======================= host ==============================================
extern "C" void kernel_launch(void* const* d_in, const int* in_sizes, int n_in,
                              void* d_out, int out_size, void* d_ws, size_t ws_size,
                              hipStream_t stream)
{
    (void)in_sizes; (void)n_in; (void)out_size;
    const float* y   = (const float*)d_in[0];
    const float* Wc  = (const float*)d_in[1];
    const float* bc  = (const float*)d_in[2];
    const float* Wf  = (const float*)d_in[3];
    const float* bf  = (const float*)d_in[4];
    const float* Wr  = (const float*)d_in[5];
    const float* br  = (const float*)d_in[6];
    const float* Ws  = (const float*)d_in[7];
    const float* bs  = (const float*)d_in[8];
    const float* We1 = (const float*)d_in[9];
    const float* be1 = (const float*)d_in[10];
    const float* We2 = (const float*)d_in[11];
    const float* be2 = (const float*)d_in[12];
    float* out = (float*)d_out;
    char* ws = (char*)d_ws;

    size_t o = 0;
    auto alloc = [&](size_t bytes) { size_t r = o; o += (bytes + 1023) & ~(size_t)1023; return r; };
    size_t o_reg = alloc(NT_ * 512 * 2);       // y_t [NT][512]; later g [30][NT][16]
    size_t o_xa  = alloc(NT_ * 32 * 2);
    size_t o_xb  = alloc(NT_ * 32 * 2);
    size_t o_wcp = alloc(24576 * 2);
    size_t o_wfp = alloc(61440 * 2);
    size_t o_wrp = alloc(30720 * 2);
    size_t o_wst = alloc(122880 * 2);
    size_t o_we1 = alloc(65536 * 2);
    size_t o_we2 = alloc(65536 * 2);
    size_t o_bss = alloc(1024);
    size_t need_new = o;   // ~151.7 MB

    if (ws_size >= need_new) {
        ushort* y_t  = (ushort*)(ws + o_reg);
        ushort* g    = (ushort*)(ws + o_reg);   // overlays y_t after init
        ushort* xba  = (ushort*)(ws + o_xa);
        ushort* xbb  = (ushort*)(ws + o_xb);
        ushort* wcp  = (ushort*)(ws + o_wcp);
        ushort* wfp  = (ushort*)(ws + o_wfp);
        ushort* wrp  = (ushort*)(ws + o_wrp);
        ushort* wsF  = (ushort*)(ws + o_wst);
        ushort* we1F = (ushort*)(ws + o_we1);
        ushort* we2F = (ushort*)(ws + o_we2);
        float*  bsSum= (float*)(ws + o_bss);

        prep_w_kernel<<<1448, 256, 0, stream>>>(Wc, Wf, Wr, Ws, We1, We2,
                                                wcp, wfp, wrp, wsF, we1F, we2F);
        bsum_kernel<<<1, 256, 0, stream>>>(bs, bsSum);
        prep_y_kernel<<<2048, 256, 0, stream>>>(y, y_t);
        init_gemm_kernel<<<512, 256, 0, stream>>>(wcp, y_t, bc, xba);

        ushort* xbin = xba; ushort* xbout = xbb;
        for (int i = 0; i < NL_; ++i) {
            int d = 1 << (i % 10);
            layer_mfma_kernel<<<1024, 256, 0, stream>>>(
                xbin, xbout, g + (size_t)i * NT_ * 16,
                wfp + (size_t)i * 2048, wrp + (size_t)i * 1024,
                bf + i * 32, br + i * 32, d);
            ushort* tmp = xbin; xbin = xbout; xbout = tmp;
        }

        tail_kernel<<<2048, 256, 0, stream>>>(g, bsSum, wsF, we1F, we2F,
                                              be1, be2, out);
        return;
    }

    size_t xbytes = (size_t)B_ * RC_ * T_ * sizeof(float);
    size_t need_f32 = 2 * xbytes + (size_t)NL_ * B_ * KH_ * T_ * 4 + 1024;
    if (ws_size >= need_f32)
        run_pipeline_old<float>(y, Wc, bc, Wf, bf, Wr, br, Ws, bs, We1, be1, We2, be2, out, ws, stream);
    else
        run_pipeline_old<__hip_bfloat16>(y, Wc, bc, Wf, bf, Wr, br, Ws, bs, We1, be1, We2, be2, out, ws, stream);
}

// Round 8
// 653.649 us; speedup vs baseline: 5.4636x; 1.0566x over previous
//
#include <hip/hip_runtime.h>
#include <hip/hip_bf16.h>

// WaveNet forward, MI355X — MFMA pipeline v4.
//  prep_w    : weights -> bf16 fragment layouts
//  prep_y    : y [b][256][T] fp32 -> y_t [t'][512] bf16 {hi|lo}
//  init_gemm : x0 = Wc@y + bc, K=768 = [hi|hi|lo]@[yh|yl|yh]
//  stack x3  : FUSED layers d=1..64 (7 layers) in LDS, 128-halo recompute
//  layer x9  : d=128/256/512 remain separate (t-d crosses tile)
//  tail v4   : v3 + LDS-staged coalesced output stores (fix 204MB->134MB writes)

#define B_ 4
#define T_ 32768
#define RC_ 32
#define KH_ 16
#define SC_ 256
#define CLASSES_ 256
#define NL_ 30
#define NT_ 131072L   // B_*T_

using f32x4 = __attribute__((ext_vector_type(4))) float;
using s16x8 = __attribute__((ext_vector_type(8))) short;

__device__ inline float fast_rcp(float x) { return __builtin_amdgcn_rcpf(x); }
__device__ inline float fast_sigmoid(float x) { return fast_rcp(1.f + __expf(-x)); }
__device__ inline float fast_tanh(float x) { return 1.f - 2.f * fast_rcp(__expf(2.f * x) + 1.f); }

__device__ inline ushort f2bf(float v) {
    __hip_bfloat16 h = __float2bfloat16(v);
    return __builtin_bit_cast(ushort, h);
}
__device__ inline uint pack2(float a, float b) {
    return (uint)f2bf(a) | ((uint)f2bf(b) << 16);
}
__device__ inline float bflo(uint u) { return __builtin_bit_cast(float, u << 16); }
__device__ inline float bfhi(uint u) { return __builtin_bit_cast(float, u & 0xffff0000u); }
__device__ inline s16x8 mfma_in(uint4 u) { return __builtin_bit_cast(s16x8, u); }

// ======================= prep: weights =====================================
__global__ __launch_bounds__(256) void prep_w_kernel(
    const float* __restrict__ Wc, const float* __restrict__ Wf,
    const float* __restrict__ Wr, const float* __restrict__ Ws,
    const float* __restrict__ We1, const float* __restrict__ We2,
    ushort* __restrict__ wcp, ushort* __restrict__ wfp, ushort* __restrict__ wrp,
    ushort* __restrict__ wsF, ushort* __restrict__ we1F, ushort* __restrict__ we2F)
{
    int j = blockIdx.x * 256 + threadIdx.x;
    if (j < 24576) {                       // WcP[32][768] = [hi | hi | lo]
        int m = j / 768, k = j % 768;
        float v = Wc[m * 256 + (k & 255)];
        if (k < 512) wcp[j] = f2bf(v);
        else {
            float hi = __bfloat162float(__float2bfloat16(v));
            wcp[j] = f2bf(v - hi);
        }
    } else if (j < 86016) {                // WfP[30][2][32][32]  (tap, out c, in ci)
        int e = j - 24576;
        int i = e >> 11; int r = e & 2047;
        int tap = r >> 10, c = (r >> 5) & 31, ci = r & 31;
        wfp[e] = f2bf(Wf[((size_t)(i * 32 + c) * 32 + ci) * 2 + tap]);
    } else if (j < 116736) {               // WrP[30][32][32] zero-padded k>=16
        int e = j - 86016;
        int i = e >> 10; int c = (e >> 5) & 31; int k = e & 31;
        wrp[e] = (k < 16) ? f2bf(Wr[(size_t)(i * 32 + c) * 16 + k]) : (ushort)0;
    } else if (j < 239616) {               // wsF fragment-major
        int e = j - 116736;
        int jj = e & 7, lane = (e >> 3) & 63, mrow = (e >> 9) & 15, kc = e >> 13;
        int m = mrow * 16 + (lane & 15);
        int k = kc * 32 + (lane >> 4) * 8 + jj;      // 0..479
        int i = k >> 4, ci = k & 15;
        wsF[e] = f2bf(Ws[((size_t)i * 256 + m) * 16 + ci]);
    } else if (j < 305152) {               // we1F fragment-major
        int e = j - 239616;
        int jj = e & 7, lane = (e >> 3) & 63, mrow = (e >> 9) & 15, kc = e >> 13;
        int m = mrow * 16 + (lane & 15);
        int k = kc * 32 + (lane >> 4) * 8 + jj;
        we1F[e] = f2bf(We1[m * 256 + k]);
    } else if (j < 370688) {               // we2F fragment-major
        int e = j - 305152;
        int jj = e & 7, lane = (e >> 3) & 63, mrow = (e >> 9) & 15, kc = e >> 13;
        int m = mrow * 16 + (lane & 15);
        int k = kc * 32 + (lane >> 4) * 8 + jj;
        we2F[e] = f2bf(We2[m * 256 + k]);
    }
}

__global__ void bsum_kernel(const float* __restrict__ bs, float* __restrict__ bsSum) {
    int s = threadIdx.x;
    float v = 0.f;
    #pragma unroll
    for (int i = 0; i < NL_; ++i) v += bs[i * SC_ + s];
    bsSum[s] = v;
}

// ======================= prep: y transpose + hi/lo split ===================
__global__ __launch_bounds__(256) void prep_y_kernel(
    const float* __restrict__ y, ushort* __restrict__ y_t)
{
    __shared__ float lds[32][65];
    int tid = threadIdx.x;
    int b = blockIdx.x >> 9;
    long t0 = (long)(blockIdx.x & 511) * 64;
    for (int cc = 0; cc < 8; ++cc) {
        int c = cc * 32 + (tid >> 3);
        int tp = (tid & 7) * 8;
        const float* src = y + ((size_t)b * 256 + c) * T_ + t0 + tp;
        float4 v0 = *(const float4*)src;
        float4 v1 = *(const float4*)(src + 4);
        lds[tid >> 3][tp + 0] = v0.x; lds[tid >> 3][tp + 1] = v0.y;
        lds[tid >> 3][tp + 2] = v0.z; lds[tid >> 3][tp + 3] = v0.w;
        lds[tid >> 3][tp + 4] = v1.x; lds[tid >> 3][tp + 5] = v1.y;
        lds[tid >> 3][tp + 6] = v1.z; lds[tid >> 3][tp + 7] = v1.w;
        __syncthreads();
        int t = tid & 63, cp = tid >> 6;
        float v[8];
        #pragma unroll
        for (int jj = 0; jj < 8; ++jj) v[jj] = lds[cp * 8 + jj][t];
        uint hi[4], lo[4];
        #pragma unroll
        for (int jj = 0; jj < 4; ++jj) {
            float a = v[2 * jj], bv = v[2 * jj + 1];
            float ah = __bfloat162float(__float2bfloat16(a));
            float bh = __bfloat162float(__float2bfloat16(bv));
            hi[jj] = pack2(a, bv);
            lo[jj] = pack2(a - ah, bv - bh);
        }
        ushort* dst = y_t + ((size_t)b * T_ + t0 + t) * 512 + cc * 32 + cp * 8;
        *(uint4*)dst = make_uint4(hi[0], hi[1], hi[2], hi[3]);
        *(uint4*)(dst + 256) = make_uint4(lo[0], lo[1], lo[2], lo[3]);
        __syncthreads();
    }
}

// ======================= init GEMM: x0 = Wc@y + bc =========================
__global__ __launch_bounds__(256) void init_gemm_kernel(
    const ushort* __restrict__ wcp, const ushort* __restrict__ y_t,
    const float* __restrict__ bc, ushort* __restrict__ x0)
{
    __shared__ ushort sa[2][32 * 40];
    __shared__ ushort sb[2][256 * 40];
    int tid = threadIdx.x;
    int wid = tid >> 6, lane = tid & 63, q = lane >> 4, ln = lane & 15;
    long n0 = (long)blockIdx.x * 256;

    uint4 ar0, ar1, br0, br1, br2, br3;
    auto load_tile = [&](int kc) {
        int k0 = kc * 32;
        int koff = (k0 < 512) ? k0 : k0 - 512;
        if (tid < 64) {
            int m = tid >> 1, h = tid & 1;
            const uint4* s = (const uint4*)(wcp + m * 768 + k0 + h * 16);
            ar0 = s[0]; ar1 = s[1];
        }
        const uint4* sB = (const uint4*)(y_t + (n0 + tid) * 512 + koff);
        br0 = sB[0]; br1 = sB[1]; br2 = sB[2]; br3 = sB[3];
    };
    auto store_tile = [&](int buf) {
        if (tid < 64) {
            int m = tid >> 1, h = tid & 1;
            *(uint4*)&sa[buf][m * 40 + h * 16] = ar0;
            *(uint4*)&sa[buf][m * 40 + h * 16 + 8] = ar1;
        }
        *(uint4*)&sb[buf][tid * 40 + 0]  = br0;
        *(uint4*)&sb[buf][tid * 40 + 8]  = br1;
        *(uint4*)&sb[buf][tid * 40 + 16] = br2;
        *(uint4*)&sb[buf][tid * 40 + 24] = br3;
    };

    f32x4 acc[2][4];
    #pragma unroll
    for (int mi = 0; mi < 2; ++mi) {
        f32x4 bv = *(const f32x4*)&bc[mi * 16 + 4 * q];
        #pragma unroll
        for (int ni = 0; ni < 4; ++ni) acc[mi][ni] = bv;
    }
    load_tile(0);
    for (int kc = 0; kc < 24; ++kc) {
        int buf = kc & 1;
        store_tile(buf);
        __syncthreads();
        if (kc + 1 < 24) load_tile(kc + 1);
        s16x8 af[2];
        #pragma unroll
        for (int mi = 0; mi < 2; ++mi)
            af[mi] = mfma_in(*(const uint4*)&sa[buf][(mi * 16 + ln) * 40 + q * 8]);
        #pragma unroll
        for (int ni = 0; ni < 4; ++ni) {
            s16x8 bfr = mfma_in(*(const uint4*)&sb[buf][(wid * 64 + ni * 16 + ln) * 40 + q * 8]);
            #pragma unroll
            for (int mi = 0; mi < 2; ++mi)
                acc[mi][ni] = __builtin_amdgcn_mfma_f32_16x16x32_bf16(af[mi], bfr, acc[mi][ni], 0, 0, 0);
        }
        __syncthreads();
    }
    #pragma unroll
    for (int mi = 0; mi < 2; ++mi) {
        int ch = mi * 16 + 4 * q;
        #pragma unroll
        for (int ni = 0; ni < 4; ++ni) {
            long t = n0 + wid * 64 + ni * 16 + ln;
            f32x4 v = acc[mi][ni];
            uint2 pk; pk.x = pack2(v[0], v[1]); pk.y = pack2(v[2], v[3]);
            *(uint2*)&x0[t * 32 + ch] = pk;
        }
    }
}

// ======================= fused stack: layers d=1..64 =======================
// Block: 256 output t + 128 halo = 384-row LDS tile (pad 40 ushorts/row).
// 7 layers in LDS ping-pong; one barrier/layer. Mask rule (t&(T-1))>=d makes
// halo/boundary garbage provably unused; halo values bitwise-match neighbors.
__global__ __launch_bounds__(256) void stack_kernel(
    const ushort* __restrict__ xb_in, ushort* __restrict__ xb_out,
    ushort* __restrict__ g_out,       // pre-offset to layer i0
    const ushort* __restrict__ wfp,   // pre-offset
    const ushort* __restrict__ wrp,   // pre-offset
    const float* __restrict__ bfp, const float* __restrict__ brp)
{
    __shared__ ushort xl[2][384 * 40];   // 61440 B
    int tid = threadIdx.x;
    int wid = tid >> 6, lane = tid & 63, q = lane >> 4, ln = lane & 15;
    long bo = (long)blockIdx.x * 256;

    // load [bo-128, bo+256) -> xl[0]; row r = t' = bo-128+r
    #pragma unroll
    for (int k = 0; k < 6; ++k) {
        int idx = k * 256 + tid;
        int row = idx >> 2, part = idx & 3;
        long t = bo - 128 + row;
        if (t < 0) t = 0;
        uint4 v = *(const uint4*)&xb_in[t * 32 + part * 8];
        *(uint4*)&xl[0][row * 40 + part * 8] = v;
    }
    __syncthreads();

    const float inv_s2 = 0.70710678118654752f;
    int cur = 0;
    for (int j = 0; j < 7; ++j) {
        int d = 1 << j;
        s16x8 wfA[2][2], wrA[2];
        #pragma unroll
        for (int mb = 0; mb < 2; ++mb) {
            #pragma unroll
            for (int tap = 0; tap < 2; ++tap)
                wfA[mb][tap] = mfma_in(*(const uint4*)&wfp[(size_t)j * 2048 +
                    (tap * 32 + mb * 16 + ln) * 32 + q * 8]);
            wrA[mb] = mfma_in(*(const uint4*)&wrp[(size_t)j * 1024 + (mb * 16 + ln) * 32 + q * 8]);
        }
        f32x4 bfv0 = *(const f32x4*)&bfp[j * 32 + 4 * q];
        f32x4 bfv1 = *(const f32x4*)&bfp[j * 32 + 16 + 4 * q];
        f32x4 brv0 = *(const f32x4*)&brp[j * 32 + 4 * q];
        f32x4 brv1 = *(const f32x4*)&brp[j * 32 + 16 + 4 * q];
        ushort* ga = g_out + (size_t)j * NT_ * 16;

        #pragma unroll
        for (int nb = 0; nb < 6; ++nb) {
            int tb = wid * 96 + nb * 16;
            int tl = tb + ln;
            long t = bo - 128 + tl;
            bool vok = ((int)(t & (T_ - 1)) >= d);
            int rd = tl - d; if (rd < 0) rd = 0;
            uint4 u0 = *(const uint4*)&xl[cur][rd * 40 + 8 * q];
            if (!vok) u0 = make_uint4(0, 0, 0, 0);
            uint4 u1 = *(const uint4*)&xl[cur][tl * 40 + 8 * q];
            s16x8 b0 = mfma_in(u0), b1 = mfma_in(u1);

            f32x4 h0 = {}, h1 = {};
            h0 = __builtin_amdgcn_mfma_f32_16x16x32_bf16(wfA[0][0], b0, h0, 0, 0, 0);
            h0 = __builtin_amdgcn_mfma_f32_16x16x32_bf16(wfA[0][1], b1, h0, 0, 0, 0);
            h1 = __builtin_amdgcn_mfma_f32_16x16x32_bf16(wfA[1][0], b0, h1, 0, 0, 0);
            h1 = __builtin_amdgcn_mfma_f32_16x16x32_bf16(wfA[1][1], b1, h1, 0, 0, 0);

            float g[4];
            #pragma unroll
            for (int r = 0; r < 4; ++r)
                g[r] = fast_tanh(h0[r] + bfv0[r]) * fast_sigmoid(h1[r] + bfv1[r]);
            uint p01 = pack2(g[0], g[1]), p23 = pack2(g[2], g[3]);
            if (tb >= 128) {
                uint2 gst; gst.x = p01; gst.y = p23;
                *(uint2*)&ga[t * 16 + 4 * q] = gst;
            }

            int sA = q * 32 + ln;
            uint f0 = (uint)__shfl((int)p01, sA);
            uint f1 = (uint)__shfl((int)p23, sA);
            uint f2 = (uint)__shfl((int)p01, sA + 16);
            uint f3 = (uint)__shfl((int)p23, sA + 16);
            s16x8 gb = mfma_in(make_uint4(f0, f1, f2, f3));

            f32x4 rr0 = {}, rr1 = {};
            rr0 = __builtin_amdgcn_mfma_f32_16x16x32_bf16(wrA[0], gb, rr0, 0, 0, 0);
            rr1 = __builtin_amdgcn_mfma_f32_16x16x32_bf16(wrA[1], gb, rr1, 0, 0, 0);

            uint2 xr0 = *(const uint2*)&xl[cur][tl * 40 + 4 * q];
            uint2 xr1 = *(const uint2*)&xl[cur][tl * 40 + 16 + 4 * q];
            float o00 = (rr0[0] + brv0[0] + bflo(xr0.x)) * inv_s2;
            float o01 = (rr0[1] + brv0[1] + bfhi(xr0.x)) * inv_s2;
            float o02 = (rr0[2] + brv0[2] + bflo(xr0.y)) * inv_s2;
            float o03 = (rr0[3] + brv0[3] + bfhi(xr0.y)) * inv_s2;
            float o10 = (rr1[0] + brv1[0] + bflo(xr1.x)) * inv_s2;
            float o11 = (rr1[1] + brv1[1] + bfhi(xr1.x)) * inv_s2;
            float o12 = (rr1[2] + brv1[2] + bflo(xr1.y)) * inv_s2;
            float o13 = (rr1[3] + brv1[3] + bfhi(xr1.y)) * inv_s2;
            uint2 xp0; xp0.x = pack2(o00, o01); xp0.y = pack2(o02, o03);
            uint2 xp1; xp1.x = pack2(o10, o11); xp1.y = pack2(o12, o13);
            if (j < 6) {
                *(uint2*)&xl[cur ^ 1][tl * 40 + 4 * q] = xp0;
                *(uint2*)&xl[cur ^ 1][tl * 40 + 16 + 4 * q] = xp1;
            } else if (tb >= 128) {
                *(uint2*)&xb_out[t * 32 + 4 * q] = xp0;
                *(uint2*)&xb_out[t * 32 + 16 + 4 * q] = xp1;
            }
        }
        __syncthreads();
        cur ^= 1;
    }
}

// ======================= layer (MFMA, bf16 x) — d>=128 =====================
__global__ __launch_bounds__(256) void layer_mfma_kernel(
    const ushort* __restrict__ xb_in, ushort* __restrict__ xb_out,
    ushort* __restrict__ g_out,
    const ushort* __restrict__ wfp, const ushort* __restrict__ wrp,
    const float* __restrict__ bfp, const float* __restrict__ brp, int d)
{
    int tid = threadIdx.x;
    int wid = tid >> 6, lane = tid & 63, q = lane >> 4, ln = lane & 15;
    long tw = (long)blockIdx.x * 128 + wid * 32;

    s16x8 wfA[2][2], wrA[2];
    #pragma unroll
    for (int mb = 0; mb < 2; ++mb) {
        #pragma unroll
        for (int tap = 0; tap < 2; ++tap)
            wfA[mb][tap] = mfma_in(*(const uint4*)&wfp[(tap * 32 + mb * 16 + ln) * 32 + q * 8]);
        wrA[mb] = mfma_in(*(const uint4*)&wrp[(mb * 16 + ln) * 32 + q * 8]);
    }
    f32x4 bfv0 = *(const f32x4*)&bfp[4 * q];
    f32x4 bfv1 = *(const f32x4*)&bfp[16 + 4 * q];
    f32x4 brv0 = *(const f32x4*)&brp[4 * q];
    f32x4 brv1 = *(const f32x4*)&brp[16 + 4 * q];
    const float inv_s2 = 0.70710678118654752f;

    #pragma unroll
    for (int nb = 0; nb < 2; ++nb) {
        long t = tw + nb * 16 + ln;
        bool vok = ((int)(t & (T_ - 1)) >= d);
        long r0 = vok ? (t - d) : t;
        uint4 u0 = *(const uint4*)&xb_in[r0 * 32 + 8 * q];
        if (!vok) u0 = make_uint4(0, 0, 0, 0);
        uint4 u1 = *(const uint4*)&xb_in[t * 32 + 8 * q];
        s16x8 b0 = mfma_in(u0), b1 = mfma_in(u1);

        f32x4 h0 = {}, h1 = {};
        h0 = __builtin_amdgcn_mfma_f32_16x16x32_bf16(wfA[0][0], b0, h0, 0, 0, 0);
        h0 = __builtin_amdgcn_mfma_f32_16x16x32_bf16(wfA[0][1], b1, h0, 0, 0, 0);
        h1 = __builtin_amdgcn_mfma_f32_16x16x32_bf16(wfA[1][0], b0, h1, 0, 0, 0);
        h1 = __builtin_amdgcn_mfma_f32_16x16x32_bf16(wfA[1][1], b1, h1, 0, 0, 0);

        float g[4];
        #pragma unroll
        for (int r = 0; r < 4; ++r)
            g[r] = fast_tanh(h0[r] + bfv0[r]) * fast_sigmoid(h1[r] + bfv1[r]);
        uint p01 = pack2(g[0], g[1]), p23 = pack2(g[2], g[3]);
        uint2 gst; gst.x = p01; gst.y = p23;
        *(uint2*)&g_out[t * 16 + 4 * q] = gst;

        int sA = q * 32 + ln;
        uint f0 = (uint)__shfl((int)p01, sA);
        uint f1 = (uint)__shfl((int)p23, sA);
        uint f2 = (uint)__shfl((int)p01, sA + 16);
        uint f3 = (uint)__shfl((int)p23, sA + 16);
        s16x8 gb = mfma_in(make_uint4(f0, f1, f2, f3));

        f32x4 rr0 = {}, rr1 = {};
        rr0 = __builtin_amdgcn_mfma_f32_16x16x32_bf16(wrA[0], gb, rr0, 0, 0, 0);
        rr1 = __builtin_amdgcn_mfma_f32_16x16x32_bf16(wrA[1], gb, rr1, 0, 0, 0);

        uint2 xr0 = *(const uint2*)&xb_in[t * 32 + 4 * q];
        uint2 xr1 = *(const uint2*)&xb_in[t * 32 + 16 + 4 * q];
        float o00 = (rr0[0] + brv0[0] + bflo(xr0.x)) * inv_s2;
        float o01 = (rr0[1] + brv0[1] + bfhi(xr0.x)) * inv_s2;
        float o02 = (rr0[2] + brv0[2] + bflo(xr0.y)) * inv_s2;
        float o03 = (rr0[3] + brv0[3] + bfhi(xr0.y)) * inv_s2;
        float o10 = (rr1[0] + brv1[0] + bflo(xr1.x)) * inv_s2;
        float o11 = (rr1[1] + brv1[1] + bfhi(xr1.x)) * inv_s2;
        float o12 = (rr1[2] + brv1[2] + bflo(xr1.y)) * inv_s2;
        float o13 = (rr1[3] + brv1[3] + bfhi(xr1.y)) * inv_s2;
        uint2 xp0; xp0.x = pack2(o00, o01); xp0.y = pack2(o02, o03);
        uint2 xp1; xp1.x = pack2(o10, o11); xp1.y = pack2(o12, o13);
        *(uint2*)&xb_out[t * 32 + 4 * q] = xp0;
        *(uint2*)&xb_out[t * 32 + 16 + 4 * q] = xp1;
    }
}

// ======================= fused tail v4 =====================================
// v3 + coalesced epilogue: stage f32 output through LDS (16-t chunks, pad 260)
// so global stores are contiguous 1KB rows (kills the 1.5x write amplification).
__global__ __launch_bounds__(256, 4) void tail_kernel(
    const ushort* __restrict__ g_all, const float* __restrict__ bsSum,
    const ushort* __restrict__ wsF, const ushort* __restrict__ we1F,
    const ushort* __restrict__ we2F, const float* __restrict__ be1,
    const float* __restrict__ be2, float* __restrict__ out)
{
    __shared__ ushort stg[2][2048];   // B-frag staging [4 ni][64 lane][8]
    __shared__ ushort pq[16384];      // p/q frags; later f32 out staging [16][260]
    int tid = threadIdx.x;
    int wid = tid >> 6, lane = tid & 63, q = lane >> 4, ln = lane & 15;
    long n0 = (long)blockIdx.x * 64;
    int wrow = wid * 64;

    int sn = tid & 63, sip = (tid >> 6) & 1, shalf = tid >> 7;
    int sdst = ((sn >> 4) * 64 + (sip * 2 + shalf) * 16 + (sn & 15)) * 8;

    f32x4 acc[4][4];
    #pragma unroll
    for (int mi = 0; mi < 4; ++mi) {
        f32x4 bv = *(const f32x4*)&bsSum[wrow + mi * 16 + 4 * q];
        #pragma unroll
        for (int ni = 0; ni < 4; ++ni) acc[mi][ni] = bv;
    }

    // ---------- phase 1: skip (K=480) ----------
    uint4 ld = *(const uint4*)(g_all + ((size_t)sip * NT_ + n0 + sn) * 16 + shalf * 8);
    *(uint4*)&stg[0][sdst] = ld;
    for (int kc = 0; kc < 15; ++kc) {
        __syncthreads();
        if (kc < 14)
            ld = *(const uint4*)(g_all +
                ((size_t)(2 * (kc + 1) + sip) * NT_ + n0 + sn) * 16 + shalf * 8);
        s16x8 af[4], bfr[4];
        #pragma unroll
        for (int mi = 0; mi < 4; ++mi)
            af[mi] = mfma_in(*(const uint4*)(wsF +
                (((size_t)kc * 16 + wid * 4 + mi) * 64 + lane) * 8));
        #pragma unroll
        for (int ni = 0; ni < 4; ++ni)
            bfr[ni] = mfma_in(*(const uint4*)&stg[kc & 1][(ni * 64 + lane) * 8]);
        #pragma unroll
        for (int ni = 0; ni < 4; ++ni)
            #pragma unroll
            for (int mi = 0; mi < 4; ++mi)
                acc[mi][ni] = __builtin_amdgcn_mfma_f32_16x16x32_bf16(
                    af[mi], bfr[ni], acc[mi][ni], 0, 0, 0);
        if (kc < 14) *(uint4*)&stg[(kc + 1) & 1][sdst] = ld;
    }
    #pragma unroll
    for (int mi = 0; mi < 4; ++mi) {
        int ch = wrow + mi * 16 + 4 * q;
        int dbase = ((ch >> 5) * 4) * 512 + (((ch & 31) >> 3) * 16 + ln) * 8 + (ch & 7);
        #pragma unroll
        for (int ni = 0; ni < 4; ++ni) {
            f32x4 v = acc[mi][ni];
            uint2 pk;
            pk.x = pack2(fmaxf(v[0], 0.f), fmaxf(v[1], 0.f));
            pk.y = pack2(fmaxf(v[2], 0.f), fmaxf(v[3], 0.f));
            *(uint2*)&pq[dbase + ni * 512] = pk;
        }
    }
    __syncthreads();

    // ---------- phase 2: e1 ----------
    #pragma unroll
    for (int mi = 0; mi < 4; ++mi) {
        f32x4 bv = *(const f32x4*)&be1[wrow + mi * 16 + 4 * q];
        #pragma unroll
        for (int ni = 0; ni < 4; ++ni) acc[mi][ni] = bv;
    }
    for (int kc = 0; kc < 8; ++kc) {
        s16x8 af[4], bfr[4];
        #pragma unroll
        for (int mi = 0; mi < 4; ++mi)
            af[mi] = mfma_in(*(const uint4*)(we1F +
                (((size_t)kc * 16 + wid * 4 + mi) * 64 + lane) * 8));
        #pragma unroll
        for (int ni = 0; ni < 4; ++ni)
            bfr[ni] = mfma_in(*(const uint4*)&pq[(kc * 4 + ni) * 512 + lane * 8]);
        #pragma unroll
        for (int ni = 0; ni < 4; ++ni)
            #pragma unroll
            for (int mi = 0; mi < 4; ++mi)
                acc[mi][ni] = __builtin_amdgcn_mfma_f32_16x16x32_bf16(
                    af[mi], bfr[ni], acc[mi][ni], 0, 0, 0);
    }
    __syncthreads();
    #pragma unroll
    for (int mi = 0; mi < 4; ++mi) {
        int ch = wrow + mi * 16 + 4 * q;
        int dbase = ((ch >> 5) * 4) * 512 + (((ch & 31) >> 3) * 16 + ln) * 8 + (ch & 7);
        #pragma unroll
        for (int ni = 0; ni < 4; ++ni) {
            f32x4 v = acc[mi][ni];
            uint2 pk;
            pk.x = pack2(fmaxf(v[0], 0.f), fmaxf(v[1], 0.f));
            pk.y = pack2(fmaxf(v[2], 0.f), fmaxf(v[3], 0.f));
            *(uint2*)&pq[dbase + ni * 512] = pk;
        }
    }
    __syncthreads();

    // ---------- phase 3: e2 ----------
    #pragma unroll
    for (int mi = 0; mi < 4; ++mi) {
        f32x4 bv = *(const f32x4*)&be2[wrow + mi * 16 + 4 * q];
        #pragma unroll
        for (int ni = 0; ni < 4; ++ni) acc[mi][ni] = bv;
    }
    for (int kc = 0; kc < 8; ++kc) {
        s16x8 af[4], bfr[4];
        #pragma unroll
        for (int mi = 0; mi < 4; ++mi)
            af[mi] = mfma_in(*(const uint4*)(we2F +
                (((size_t)kc * 16 + wid * 4 + mi) * 64 + lane) * 8));
        #pragma unroll
        for (int ni = 0; ni < 4; ++ni)
            bfr[ni] = mfma_in(*(const uint4*)&pq[(kc * 4 + ni) * 512 + lane * 8]);
        #pragma unroll
        for (int ni = 0; ni < 4; ++ni)
            #pragma unroll
            for (int mi = 0; mi < 4; ++mi)
                acc[mi][ni] = __builtin_amdgcn_mfma_f32_16x16x32_bf16(
                    af[mi], bfr[ni], acc[mi][ni], 0, 0, 0);
    }

    // ---------- coalesced epilogue: 4 chunks of 16 t through LDS ----------
    float* pqf = (float*)pq;          // [16][260] f32
    #pragma unroll
    for (int c = 0; c < 4; ++c) {     // t_local = c*16 + ln  (chunk c == ni)
        __syncthreads();              // prior pq readers (ph3 / prev chunk) done
        #pragma unroll
        for (int mi = 0; mi < 4; ++mi)
            *(f32x4*)&pqf[ln * 260 + wrow + mi * 16 + 4 * q] = acc[mi][c];
        __syncthreads();
        #pragma unroll
        for (int k = 0; k < 4; ++k) {
            int pos = k * 256 + tid;
            int row = pos >> 6, col = (pos & 63) * 4;
            *(f32x4*)&out[(n0 + c * 16 + row) * 256 + col] =
                *(const f32x4*)&pqf[row * 260 + col];
        }
    }
}

// ======================= host ==============================================
extern "C" void kernel_launch(void* const* d_in, const int* in_sizes, int n_in,
                              void* d_out, int out_size, void* d_ws, size_t ws_size,
                              hipStream_t stream)
{
    (void)in_sizes; (void)n_in; (void)out_size; (void)ws_size;
    const float* y   = (const float*)d_in[0];
    const float* Wc  = (const float*)d_in[1];
    const float* bc  = (const float*)d_in[2];
    const float* Wf  = (const float*)d_in[3];
    const float* bf  = (const float*)d_in[4];
    const float* Wr  = (const float*)d_in[5];
    const float* br  = (const float*)d_in[6];
    const float* Ws  = (const float*)d_in[7];
    const float* bs  = (const float*)d_in[8];
    const float* We1 = (const float*)d_in[9];
    const float* be1 = (const float*)d_in[10];
    const float* We2 = (const float*)d_in[11];
    const float* be2 = (const float*)d_in[12];
    float* out = (float*)d_out;
    char* ws = (char*)d_ws;

    size_t o = 0;
    auto alloc = [&](size_t bytes) { size_t r = o; o += (bytes + 1023) & ~(size_t)1023; return r; };
    size_t o_reg = alloc(NT_ * 512 * 2);       // y_t [NT][512]; later g [30][NT][16]
    size_t o_xa  = alloc(NT_ * 32 * 2);
    size_t o_xb  = alloc(NT_ * 32 * 2);
    size_t o_wcp = alloc(24576 * 2);
    size_t o_wfp = alloc(61440 * 2);
    size_t o_wrp = alloc(30720 * 2);
    size_t o_wst = alloc(122880 * 2);
    size_t o_we1 = alloc(65536 * 2);
    size_t o_we2 = alloc(65536 * 2);
    size_t o_bss = alloc(1024);

    ushort* y_t  = (ushort*)(ws + o_reg);
    ushort* g    = (ushort*)(ws + o_reg);   // overlays y_t after init
    ushort* xba  = (ushort*)(ws + o_xa);
    ushort* xbb  = (ushort*)(ws + o_xb);
    ushort* wcp  = (ushort*)(ws + o_wcp);
    ushort* wfp  = (ushort*)(ws + o_wfp);
    ushort* wrp  = (ushort*)(ws + o_wrp);
    ushort* wsF  = (ushort*)(ws + o_wst);
    ushort* we1F = (ushort*)(ws + o_we1);
    ushort* we2F = (ushort*)(ws + o_we2);
    float*  bsSum= (float*)(ws + o_bss);

    prep_w_kernel<<<1448, 256, 0, stream>>>(Wc, Wf, Wr, Ws, We1, We2,
                                            wcp, wfp, wrp, wsF, we1F, we2F);
    bsum_kernel<<<1, 256, 0, stream>>>(bs, bsSum);
    prep_y_kernel<<<2048, 256, 0, stream>>>(y, y_t);
    init_gemm_kernel<<<512, 256, 0, stream>>>(wcp, y_t, bc, xba);

    ushort* xbin = xba; ushort* xbout = xbb;
    for (int s = 0; s < 3; ++s) {
        int i0 = s * 10;
        stack_kernel<<<512, 256, 0, stream>>>(
            xbin, xbout, g + (size_t)i0 * NT_ * 16,
            wfp + (size_t)i0 * 2048, wrp + (size_t)i0 * 1024,
            bf + i0 * 32, br + i0 * 32);
        { ushort* tmp = xbin; xbin = xbout; xbout = tmp; }
        for (int jj = 7; jj < 10; ++jj) {
            int i = i0 + jj;
            int d = 1 << jj;   // 128, 256, 512
            layer_mfma_kernel<<<1024, 256, 0, stream>>>(
                xbin, xbout, g + (size_t)i * NT_ * 16,
                wfp + (size_t)i * 2048, wrp + (size_t)i * 1024,
                bf + i * 32, br + i * 32, d);
            { ushort* tmp = xbin; xbin = xbout; xbout = tmp; }
        }
    }

    tail_kernel<<<2048, 256, 0, stream>>>(g, bsSum, wsF, we1F, we2F,
                                          be1, be2, out);
}